// Round 7
// baseline (1592.449 us; speedup 1.0000x reference)
//
#include <hip/hip_runtime.h>
#include <math.h>

typedef unsigned short u16;
using short8  = __attribute__((ext_vector_type(8))) short;
using float4v = __attribute__((ext_vector_type(4))) float;

__device__ __forceinline__ float b2f(u16 u) {
    union { unsigned int i; float f; } v; v.i = ((unsigned int)u) << 16; return v.f;
}
__device__ __forceinline__ u16 f2b(float f) {
    union { float f; unsigned int i; } v; v.f = f;
    unsigned int x = v.i;
    unsigned int r = (x + 0x7fffu + ((x >> 16) & 1u)) >> 16;
    return (u16)r;
}

#define GLOAD_LDS16(gp, lp) \
    __builtin_amdgcn_global_load_lds( \
        (const __attribute__((address_space(1))) unsigned int*)(gp), \
        (__attribute__((address_space(3))) unsigned int*)(lp), 16, 0, 0)

// ---------------------------------------------------------------------------
__global__ __launch_bounds__(256) void wcvt(const float* __restrict__ s,
                                            u16* __restrict__ d, int n) {
    int stride = gridDim.x * 256;
    for (int i = blockIdx.x * 256 + threadIdx.x; i < n; i += stride)
        d[i] = f2b(s[i]);
}

// qw[64][1024] -> qwT4[d>>2][a][d&3]  (lane-coalesced float4 per 4 dims)
__global__ __launch_bounds__(256) void prep_qwT4(const float* __restrict__ qw,
                                                 float* __restrict__ qwT4) {
    int idx = blockIdx.x * 256 + threadIdx.x;   // 65536
    int a = idx >> 10, d = idx & 1023;
    qwT4[(size_t)(d >> 2) * 256 + a * 4 + (d & 3)] = qw[idx];
}

// ---------------------------------------------------------------------------
// mix2out: rmsnorm + token-shift mix, TWO mix coefficients in one pass.
// ---------------------------------------------------------------------------
__global__ __launch_bounds__(256) void mix2out(const float* __restrict__ src,
                                               const float* __restrict__ w,
                                               const float* __restrict__ f1,
                                               const float* __restrict__ f2,
                                               u16* __restrict__ out1,
                                               u16* __restrict__ out2) {
    __shared__ float redc[256], redp[256];
    int tid = threadIdx.x;
    size_t i = blockIdx.x;
    size_t ip = ((i & 4095) == 0) ? i : i - 1;
    float xc[4], xp[4];
    float ssc = 0.f, ssp = 0.f;
#pragma unroll
    for (int l = 0; l < 4; ++l) {
        int d = tid + l * 256;
        xc[l] = src[i * 1024 + d];  ssc += xc[l] * xc[l];
        xp[l] = src[ip * 1024 + d]; ssp += xp[l] * xp[l];
    }
    redc[tid] = ssc; redp[tid] = ssp; __syncthreads();
    for (int st = 128; st > 0; st >>= 1) {
        if (tid < st) { redc[tid] += redc[tid + st]; redp[tid] += redp[tid + st]; }
        __syncthreads();
    }
    float ic  = 1.f / (sqrtf(redc[0]) * (1.f / 32.f) + 1e-8f);
    float ipv = 1.f / (sqrtf(redp[0]) * (1.f / 32.f) + 1e-8f);
#pragma unroll
    for (int l = 0; l < 4; ++l) {
        int d = tid + l * 256;
        float wd = w[d];
        float xn = wd * xc[l] * ic;
        float xx = wd * xp[l] * ipv;
        float fa = f1[d], fb = f2[d];
        out1[i * 1024 + d] = f2b(fa * xn + (1.f - fa) * xx);
        out2[i * 1024 + d] = f2b(fb * xn + (1.f - fb) * xx);
    }
}

// ---------------------------------------------------------------------------
// kproj (f64 compute, f32 store in transposed Kt4 layout [b][g][key][4]).
// ---------------------------------------------------------------------------
__global__ __launch_bounds__(256) void kproj(const float* __restrict__ x,
                                             const float* __restrict__ w1,
                                             const float* __restrict__ kw,
                                             const float* __restrict__ kb,
                                             float* __restrict__ Kt4,
                                             float* __restrict__ invn) {
    __shared__ double xk[1024];
    __shared__ double red[256];
    int tid = threadIdx.x;
    size_t j = blockIdx.x;
    double ss = 0.0;
    float xc[4];
#pragma unroll
    for (int l = 0; l < 4; ++l) {
        int d = tid + l * 256;
        xc[l] = x[j * 1024 + d];
        ss += (double)xc[l] * (double)xc[l];
    }
    red[tid] = ss; __syncthreads();
    for (int st = 128; st > 0; st >>= 1) {
        if (tid < st) red[tid] += red[tid + st];
        __syncthreads();
    }
    double inv = 1.0 / (sqrt(red[0]) * (1.0 / 32.0) + 1e-8);
#pragma unroll
    for (int l = 0; l < 4; ++l) {
        int d = tid + l * 256;
        xk[d] = (double)w1[d] * (double)xc[l] * inv;
    }
    __syncthreads();
    int wv = tid >> 6, lane = tid & 63;
    int b = (int)(j >> 12), jj = (int)(j & 4095);
    for (int it = 0; it < 16; ++it) {
        int a = wv * 16 + it;
        const float* kr = kw + (size_t)a * 1024;
        double p = 0.0;
#pragma unroll
        for (int m = 0; m < 16; ++m) p += xk[lane + 64 * m] * (double)kr[lane + 64 * m];
        for (int off = 32; off; off >>= 1) p += __shfl_xor(p, off);
        if (lane == 0)
            Kt4[(((size_t)b * 16 + (a >> 2)) * 4096 + jj) * 4 + (a & 3)] = (float)(p + (double)kb[a]);
    }
    if (tid == 0) invn[j] = (float)inv;
}

// ---------------------------------------------------------------------------
// attn_w: 4 WAVES PER BLOCK, each wave = one query row, fully independent
// (zero __syncthreads; all shared arrays are per-wave slices).
// Round-4 post-mortem: occupancy was PINNED at ~6.8 blocks/CU across LDS
// 17.4K/9.2K and waves_per_eu (1,2)/(2,4) -> the limiter is a per-CU
// workgroup-slot cap on tiny 64-thread blocks, not resources. Fix: 4-wave
// blocks. LDS = 4 x (8KB f16 sc + ~1KB) ~= 36.5KB -> 4 blocks/CU x 4 waves
// = 16 waves/CU (vs 6.8). VGPR 108 allows exactly 4 waves/SIMD.
// f16 sc[] selection (validated round 4: passed, absmax unchanged): monotone
// rounding + index tie-break, exact f64 rescore of 40 candidates unchanged.
// sched_barrier(0) fences pin the prefetch-ahead schedule.
// ---------------------------------------------------------------------------
__global__ __launch_bounds__(256) void attn_w(const float* __restrict__ x,
                                  const float* __restrict__ w1,
                                  const float* __restrict__ qwT4,
                                  const float* __restrict__ qb,
                                  const float* __restrict__ Kt4,
                                  const float* __restrict__ invn,
                                  u16* __restrict__ y) {
    __shared__ _Float16 sc[4][4096];
    __shared__ double qv64s[4][64];
    __shared__ int    candL[4][40];
    __shared__ float  pwL[4][32];
    __shared__ int    idxL[4][32];

    int tid  = threadIdx.x;
    int wv   = tid >> 6;
    int lane = tid & 63;
    int i = blockIdx.x * 4 + wv;      // 4096 % 4 == 0: no wave crosses batch
    int b = i >> 12;
    int base = b << 12;

    _Float16* scw = sc[wv];
    double*   qvw = qv64s[wv];
    int*      cdw = candL[wv];
    float*    pww = pwL[wv];
    int*      idw = idxL[wv];

    // ---- Q projection: lane a computes Q[a]; 4 independent f64 accumulators
    const float* xr = x + (size_t)i * 1024;
    double qp0 = 0.0, qp1 = 0.0, qp2 = 0.0, qp3 = 0.0;
#pragma unroll 4
    for (int d4 = 0; d4 < 256; ++d4) {
        float4 w4  = *(const float4*)(w1 + d4 * 4);
        float4 x4  = *(const float4*)(xr + d4 * 4);
        float4 qw4 = *(const float4*)(qwT4 + (size_t)d4 * 256 + lane * 4);
        qp0 += (double)(w4.x * x4.x) * (double)qw4.x;
        qp1 += (double)(w4.y * x4.y) * (double)qw4.y;
        qp2 += (double)(w4.z * x4.z) * (double)qw4.z;
        qp3 += (double)(w4.w * x4.w) * (double)qw4.w;
    }
    double q = ((qp0 + qp1) + (qp2 + qp3)) * (double)invn[i] + (double)qb[lane];
    qvw[lane] = q;
    float qf = (float)q;

    // broadcast all 64 q values into per-lane registers via shuffles
    float4 qreg[16];
#pragma unroll
    for (int g = 0; g < 16; ++g) {
        qreg[g].x = __shfl(qf, 4 * g + 0);
        qreg[g].y = __shfl(qf, 4 * g + 1);
        qreg[g].z = __shfl(qf, 4 * g + 2);
        qreg[g].w = __shfl(qf, 4 * g + 3);
    }

    // ---- f32 scores (f16-rounded for selection), double-buffered 16-wide ----
    const float4* K4 = (const float4*)Kt4 + (size_t)b * 16 * 4096;
    float4 kva[16], kvb[16];
    float lv1 = -3.4e38f, lv2 = -3.4e38f;
    int   li1 = 0x7ffffffe, li2 = 0x7fffffff;
#pragma unroll
    for (int g = 0; g < 16; ++g) kva[g] = K4[g * 4096 + lane];

#define SCORE_PROC(BUF, JEXPR)                                                  \
    {                                                                           \
        int j_ = (JEXPR);                                                       \
        float s_ = 0.f;                                                         \
        _Pragma("unroll")                                                       \
        for (int g = 0; g < 16; ++g)                                            \
            s_ += qreg[g].x * BUF[g].x + qreg[g].y * BUF[g].y                   \
                + qreg[g].z * BUF[g].z + qreg[g].w * BUF[g].w;                  \
        s_ *= 0.125f;                                                           \
        if (!(s_ == s_)) s_ = -65000.0f;                                        \
        _Float16 h_ = (_Float16)s_;                                             \
        s_ = (float)h_;                                                         \
        scw[j_] = h_;                                                           \
        if (s_ > lv1 || (s_ == lv1 && j_ < li1)) {                              \
            lv2 = lv1; li2 = li1; lv1 = s_; li1 = j_;                           \
        } else if (s_ > lv2 || (s_ == lv2 && j_ < li2)) { lv2 = s_; li2 = j_; } \
    }

#pragma unroll 1
    for (int t = 0; t < 64; t += 2) {
        int j1 = (t + 1) * 64 + lane;
#pragma unroll
        for (int g = 0; g < 16; ++g) kvb[g] = K4[g * 4096 + j1];
        __builtin_amdgcn_sched_barrier(0);   // kvb loads stay ABOVE kva compute
        SCORE_PROC(kva, t * 64 + lane);
        __builtin_amdgcn_sched_barrier(0);
        if (t + 2 < 64) {
            int j2 = (t + 2) * 64 + lane;
#pragma unroll
            for (int g = 0; g < 16; ++g) kva[g] = K4[g * 4096 + j2];
        }
        __builtin_amdgcn_sched_barrier(0);   // kva loads stay ABOVE kvb compute
        SCORE_PROC(kvb, j1);
        __builtin_amdgcn_sched_barrier(0);
    }
#undef SCORE_PROC

    // ---- stage-1: extract top-40 (shuffle-only; no barriers) ----
    bool v2ok = true;
    for (int it = 0; it < 40; ++it) {
        float mv = lv1; int mi = li1;
#pragma unroll
        for (int off = 32; off >= 1; off >>= 1) {
            float ov = __shfl_xor(mv, off); int oi = __shfl_xor(mi, off);
            if (ov > mv || (ov == mv && oi < mi)) { mv = ov; mi = oi; }
        }
        if (lane == 0) cdw[it] = mi;
        if (li1 == mi) {                    // this lane owned the winner
            scw[mi] = (_Float16)(-65504.0f);
            if (v2ok) { lv1 = lv2; li1 = li2; v2ok = false; }
            else {                           // rescan own 64 slots, fresh top-2
                lv1 = -3.4e38f; li1 = 0x7ffffffe; lv2 = -3.4e38f; li2 = 0x7fffffff;
                for (int t = 0; t < 64; ++t) {
                    int j = t * 64 + lane;
                    float v = (float)scw[j];
                    if (v > lv1 || (v == lv1 && j < li1)) { lv2 = lv1; li2 = li1; lv1 = v; li1 = j; }
                    else if (v > lv2 || (v == lv2 && j < li2)) { lv2 = v; li2 = j; }
                }
                v2ok = true;
            }
        }
    }

    // ---- stage-2: f64 rescore of the 40 candidates ----
    int c = (lane < 40) ? lane : 0;
    int j = cdw[c];
    double s = 0.0;
#pragma unroll
    for (int g = 0; g < 16; ++g) {
        float4 kv = K4[g * 4096 + j];
        s += qvw[4 * g + 0] * (double)kv.x + qvw[4 * g + 1] * (double)kv.y
           + qvw[4 * g + 2] * (double)kv.z + qvw[4 * g + 3] * (double)kv.w;
    }
    s *= 0.125;
    if (lane >= 40) { s = -1.0e300; j = 0x7fffffff; }

    // ---- exact rank among the 40 (tie -> lower key index) ----
    int rank = 0;
    for (int c2 = 0; c2 < 40; ++c2) {
        double s2 = __shfl(s, c2); int j2 = __shfl(j, c2);
        if (s2 > s || (s2 == s && j2 < j)) ++rank;
    }

    // ---- f64 softmax over ranks 0..31 ----
    unsigned long long m0 = __ballot(rank == 0);
    int src = __ffsll((unsigned long long)m0) - 1;
    double mx = __shfl(s, src);
    double e = (rank < 32) ? exp(s - mx) : 0.0;
    double sum = e;
#pragma unroll
    for (int off = 1; off < 64; off <<= 1) sum += __shfl_xor(sum, off);
    if (rank < 32) {
        pww[rank] = (float)(e / sum) * invn[base + j];
        idw[rank] = j;
    }

    // ---- gather (double-buffered rows, schedule pinned) ----
    float acc[16], xga[16], xgb[16];
#pragma unroll
    for (int m = 0; m < 16; ++m) acc[m] = 0.f;
    {
        const float* x0 = x + (size_t)(base + idw[0]) * 1024;
#pragma unroll
        for (int m = 0; m < 16; ++m) xga[m] = x0[m * 64 + lane];
    }
#pragma unroll 1
    for (int k = 0; k < 32; k += 2) {
        const float* xn1 = x + (size_t)(base + idw[k + 1]) * 1024;
#pragma unroll
        for (int m = 0; m < 16; ++m) xgb[m] = xn1[m * 64 + lane];
        __builtin_amdgcn_sched_barrier(0);
        float p0 = pww[k];
#pragma unroll
        for (int m = 0; m < 16; ++m) acc[m] += p0 * xga[m];
        __builtin_amdgcn_sched_barrier(0);
        if (k + 2 < 32) {
            const float* xn2 = x + (size_t)(base + idw[k + 2]) * 1024;
#pragma unroll
            for (int m = 0; m < 16; ++m) xga[m] = xn2[m * 64 + lane];
        }
        __builtin_amdgcn_sched_barrier(0);
        float p1 = pww[k + 1];
#pragma unroll
        for (int m = 0; m < 16; ++m) acc[m] += p1 * xgb[m];
        __builtin_amdgcn_sched_barrier(0);
    }
#pragma unroll
    for (int m = 0; m < 16; ++m) {
        int d = m * 64 + lane;
        y[(size_t)i * 1024 + d] = f2b(w1[d] * acc[m]);
    }
}

// ---------------------------------------------------------------------------
// MFMA bf16 GEMM: C[M,N] = A[M,K] @ B[N,K]^T. 128x128 tile, BK=64,
// 4 waves (2x2 of 64x64), 16x16x32 MFMA, global_load_lds width-16 staging.
// T1 XCD-aware bijective block swizzle: HW linear id is by*gx+bx, and
// hw%8==bx for gx=8 -> each XCD owned one tile-COLUMN and streamed the whole
// A matrix. Chunked remap gives each XCD gx contiguous row-bands.
// EPI: 0 = bf16(acc + f32 bias[col])
//      1 = bf16(acc + bf16 aux0[g])              (in-place-safe)
//      2 = bf16(sigmoid(acc) * bf16 aux0[g])     (in-place-safe)
//      3 = f32: outF[g] = acc + f32 auxF[g]
//      4 = bf16(sigmoid(acc))
//      5 = bf16(relu(acc)^2)
//      6 = f32: outF[g] += bf16(aux0[g]) * acc   (read-modify-write)
// ---------------------------------------------------------------------------
template <int EPI>
__global__ __launch_bounds__(256) void gemm_bt(const u16* __restrict__ A,
                                               const u16* __restrict__ B,
                                               u16* outB, float* outF,
                                               const float* __restrict__ biasF,
                                               const u16* aux0,
                                               const float* auxF,
                                               int N, int K, int lda, int ldb) {
    __shared__ u16 As[128 * 64];
    __shared__ u16 Bs[128 * 64];
    int tid = threadIdx.x;
    int lane = tid & 63;
    int wv = tid >> 6;

    // T1 XCD swizzle (bijective; all grids here have nwg % 8 == 0)
    int gx = gridDim.x, gy = gridDim.y;
    int nwg = gx * gy;
    int bx = blockIdx.x, by = blockIdx.y;
    if ((nwg & 7) == 0) {
        int hw = by * gx + bx;
        int q = nwg >> 3;
        int lg = (hw & 7) * q + (hw >> 3);
        bx = lg % gx;
        by = lg / gx;
    }

    int row0 = by * 128;
    int col0 = bx * 128;
    int wm = (wv >> 1) * 64;
    int wn = (wv & 1) * 64;
    int frow = lane & 15, quad = lane >> 4;

    float4v zero = {0.f, 0.f, 0.f, 0.f};
    float4v acc[4][4];
#pragma unroll
    for (int i = 0; i < 4; ++i)
#pragma unroll
        for (int j = 0; j < 4; ++j) acc[i][j] = zero;

    for (int k0 = 0; k0 < K; k0 += 64) {
#pragma unroll
        for (int it = 0; it < 4; ++it) {
            int base = (wv * 4 + it) * 512;      // element offset (wave-uniform)
            int e = base + lane * 8;
            int r = e >> 6, c = e & 63;
            GLOAD_LDS16(A + (size_t)(row0 + r) * lda + (k0 + c), &As[base]);
            GLOAD_LDS16(B + (size_t)(col0 + r) * ldb + (k0 + c), &Bs[base]);
        }
        __syncthreads();
#pragma unroll
        for (int kk = 0; kk < 64; kk += 32) {
            short8 a_frag[4], b_frag[4];
#pragma unroll
            for (int mi = 0; mi < 4; ++mi)
                a_frag[mi] = *(const short8*)&As[(wm + mi * 16 + frow) * 64 + kk + quad * 8];
#pragma unroll
            for (int ni = 0; ni < 4; ++ni)
                b_frag[ni] = *(const short8*)&Bs[(wn + ni * 16 + frow) * 64 + kk + quad * 8];
#pragma unroll
            for (int mi = 0; mi < 4; ++mi)
#pragma unroll
                for (int ni = 0; ni < 4; ++ni)
                    acc[mi][ni] = __builtin_amdgcn_mfma_f32_16x16x32_bf16(
                        a_frag[mi], b_frag[ni], acc[mi][ni], 0, 0, 0);
        }
        __syncthreads();
    }

#pragma unroll
    for (int mi = 0; mi < 4; ++mi) {
#pragma unroll
        for (int ni = 0; ni < 4; ++ni) {
#pragma unroll
            for (int r = 0; r < 4; ++r) {
                int row = row0 + wm + mi * 16 + quad * 4 + r;
                int col = col0 + wn + ni * 16 + frow;
                size_t g = (size_t)row * N + col;
                float v = acc[mi][ni][r];
                if constexpr (EPI == 0) {
                    outB[g] = f2b(v + biasF[col]);
                } else if constexpr (EPI == 1) {
                    outB[g] = f2b(v + b2f(aux0[g]));
                } else if constexpr (EPI == 2) {
                    float sg = 1.f / (1.f + expf(-v));
                    outB[g] = f2b(sg * b2f(aux0[g]));
                } else if constexpr (EPI == 3) {
                    outF[g] = v + auxF[g];
                } else if constexpr (EPI == 4) {
                    outB[g] = f2b(1.f / (1.f + expf(-v)));
                } else if constexpr (EPI == 5) {
                    float t = v > 0.f ? v : 0.f;
                    outB[g] = f2b(t * t);
                } else if constexpr (EPI == 6) {
                    outF[g] = outF[g] + b2f(aux0[g]) * v;
                }
            }
        }
    }
}

// ---------------------------------------------------------------------------
extern "C" void kernel_launch(void* const* d_in, const int* in_sizes, int n_in,
                              void* d_out, int out_size, void* d_ws, size_t ws_size,
                              hipStream_t stream) {
    (void)in_sizes; (void)n_in; (void)out_size; (void)ws_size;
    const float* x   = (const float*)d_in[0];
    const float* n1w = (const float*)d_in[1];
    // d_in[2] tm_mix_k, d_in[5] tm_key_w are dead in the reference
    const float* tmv = (const float*)d_in[3];
    const float* tmr = (const float*)d_in[4];
    const float* vw  = (const float*)d_in[6];
    const float* rw  = (const float*)d_in[7];
    const float* ow  = (const float*)d_in[8];
    const float* qw  = (const float*)d_in[9];
    const float* qb  = (const float*)d_in[10];
    const float* skw = (const float*)d_in[11];
    const float* skb = (const float*)d_in[12];
    const float* svw = (const float*)d_in[13];
    const float* svb = (const float*)d_in[14];
    const float* sow = (const float*)d_in[15];
    const float* sob = (const float*)d_in[16];
    const float* n2w = (const float*)d_in[17];
    const float* cmk = (const float*)d_in[18];
    const float* cmr = (const float*)d_in[19];
    const float* ckw = (const float*)d_in[20];
    const float* crw = (const float*)d_in[21];
    const float* cvw = (const float*)d_in[22];

    char* W = (char*)d_ws;
    const size_t MB = 1ull << 20;
    u16*   bufA  = (u16*)(W + 0 * MB);     // 16 MB
    u16*   bufB  = (u16*)(W + 16 * MB);    // 16 MB (with C forms 32 MB k2 chunk)
    u16*   bufC  = (u16*)(W + 32 * MB);    // 16 MB
    u16*   bufD  = (u16*)(W + 48 * MB);    // 16 MB
    float* Kt4   = (float*)(W + 64 * MB);  // 2 MB  [b][g][key][4]
    float* invn  = (float*)(W + 66 * MB);  // 32 KB
    float* qwT4  = (float*)(W + 67 * MB);  // 256 KB
    u16*   ckw16 = (u16*)(W + 68 * MB);    // 8 MB
    u16*   cvw16 = (u16*)(W + 76 * MB);    // 8 MB
    u16*   svw16 = (u16*)(W + 84 * MB);    // 2 MB each below
    u16*   sow16 = (u16*)(W + 86 * MB);
    u16*   vw16  = (u16*)(W + 88 * MB);
    u16*   rw16  = (u16*)(W + 90 * MB);
    u16*   ow16  = (u16*)(W + 92 * MB);
    u16*   crw16 = (u16*)(W + 94 * MB);    // peak 96 MB
    float* x1    = (float*)d_out;          // 32 MB f32, accumulated in place

    dim3 blk(256);
    dim3 gN1024(8, 64);
    dim3 gN2048(16, 64);
    const int NW = 512;

    // weight prep
    wcvt<<<NW, blk, 0, stream>>>(svw, svw16, 1024 * 1024);
    wcvt<<<NW, blk, 0, stream>>>(sow, sow16, 1024 * 1024);
    wcvt<<<NW, blk, 0, stream>>>(vw,  vw16,  1024 * 1024);
    wcvt<<<NW, blk, 0, stream>>>(rw,  rw16,  1024 * 1024);
    wcvt<<<NW, blk, 0, stream>>>(ow,  ow16,  1024 * 1024);
    wcvt<<<NW, blk, 0, stream>>>(crw, crw16, 1024 * 1024);
    wcvt<<<NW, blk, 0, stream>>>(ckw, ckw16, 4096 * 1024);
    wcvt<<<NW, blk, 0, stream>>>(cvw, cvw16, 1024 * 4096);
    prep_qwT4<<<256, blk, 0, stream>>>(qw, qwT4);

    // --- time-mix ---
    mix2out<<<8192, blk, 0, stream>>>(x, n1w, tmv, tmr, bufA, bufC);  // vin, rin
    kproj<<<8192, blk, 0, stream>>>(x, n1w, skw, skb, Kt4, invn);
    attn_w<<<2048, blk, 0, stream>>>(x, n1w, qwT4, qb, Kt4, invn, bufB); // y
    // t = y @ sa_v_w^T + svb
    gemm_bt<0><<<gN1024, blk, 0, stream>>>(bufB, svw16, bufD, nullptr, svb, nullptr, nullptr, 1024, 1024, 1024, 1024);
    // attnO = t @ sa_o_w^T + sob  (overwrites y, dead)
    gemm_bt<0><<<gN1024, blk, 0, stream>>>(bufD, sow16, bufB, nullptr, sob, nullptr, nullptr, 1024, 1024, 1024, 1024);
    // z = vin @ tm_value_w^T + attnO   (in-place over attnO)
    gemm_bt<1><<<gN1024, blk, 0, stream>>>(bufA, vw16, bufB, nullptr, nullptr, bufB, nullptr, 1024, 1024, 1024, 1024);
    // rkv = sigmoid(rin @ tm_recept_w^T) * z   (in-place over z)
    gemm_bt<2><<<gN1024, blk, 0, stream>>>(bufC, rw16, bufB, nullptr, nullptr, bufB, nullptr, 1024, 1024, 1024, 1024);
    // x1 = x + rkv @ tm_out_w^T   (f32, into d_out)
    gemm_bt<3><<<gN1024, blk, 0, stream>>>(bufB, ow16, nullptr, x1, nullptr, nullptr, x, 1024, 1024, 1024, 1024);

    // --- channel-mix ---
    mix2out<<<8192, blk, 0, stream>>>(x1, n2w, cmk, cmr, bufA, bufC);  // kin2, rin2
    // sig2 = sigmoid(rin2 @ cm_recept_w^T) -> D
    gemm_bt<4><<<gN1024, blk, 0, stream>>>(bufC, crw16, bufD, nullptr, nullptr, nullptr, nullptr, 1024, 1024, 1024, 1024);
    // 2 chunks of 2048 DI-columns; k2 chunk (32 MB bf16) spans bufB..bufC
    for (int c = 0; c < 2; ++c) {
        const u16* ckw_c = ckw16 + (size_t)c * 2048 * 1024;  // rows c*2048.. of (4096,1024)
        const u16* cvw_c = cvw16 + (size_t)c * 2048;         // cols c*2048.. of (1024,4096)
        gemm_bt<5><<<gN2048, blk, 0, stream>>>(bufA, ckw_c, bufB, nullptr, nullptr, nullptr, nullptr,
                                               2048, 1024, 1024, 1024);
        gemm_bt<6><<<gN1024, blk, 0, stream>>>(bufB, cvw_c, nullptr, x1, nullptr, bufD, nullptr,
                                               1024, 2048, 2048, 4096);
    }
}

// Round 9
// 1523.345 us; speedup vs baseline: 1.0454x; 1.0454x over previous
//
#include <hip/hip_runtime.h>
#include <math.h>

typedef unsigned short u16;
using short8  = __attribute__((ext_vector_type(8))) short;
using float4v = __attribute__((ext_vector_type(4))) float;
using f32x2   = __attribute__((ext_vector_type(2))) float;

__device__ __forceinline__ float b2f(u16 u) {
    union { unsigned int i; float f; } v; v.i = ((unsigned int)u) << 16; return v.f;
}
__device__ __forceinline__ u16 f2b(float f) {
    union { float f; unsigned int i; } v; v.f = f;
    unsigned int x = v.i;
    unsigned int r = (x + 0x7fffu + ((x >> 16) & 1u)) >> 16;
    return (u16)r;
}

#define GLOAD_LDS16(gp, lp) \
    __builtin_amdgcn_global_load_lds( \
        (const __attribute__((address_space(1))) unsigned int*)(gp), \
        (__attribute__((address_space(3))) unsigned int*)(lp), 16, 0, 0)

// packed f32 FMA: A += B*C on a 64-bit VGPR pair (2 lanes' worth per inst)
#define PKFMA(A, B, C) \
    asm("v_pk_fma_f32 %0, %1, %2, %0" : "+v"(A) : "v"(B), "v"(C))

// ---------------------------------------------------------------------------
__global__ __launch_bounds__(256) void wcvt(const float* __restrict__ s,
                                            u16* __restrict__ d, int n) {
    int stride = gridDim.x * 256;
    for (int i = blockIdx.x * 256 + threadIdx.x; i < n; i += stride)
        d[i] = f2b(s[i]);
}

// qw[64][1024] -> qwT4[d>>2][a][d&3]  (lane-coalesced float4 per 4 dims)
__global__ __launch_bounds__(256) void prep_qwT4(const float* __restrict__ qw,
                                                 float* __restrict__ qwT4) {
    int idx = blockIdx.x * 256 + threadIdx.x;   // 65536
    int a = idx >> 10, d = idx & 1023;
    qwT4[(size_t)(d >> 2) * 256 + a * 4 + (d & 3)] = qw[idx];
}

// ---------------------------------------------------------------------------
// mix2out: rmsnorm + token-shift mix, TWO mix coefficients in one pass.
// ---------------------------------------------------------------------------
__global__ __launch_bounds__(256) void mix2out(const float* __restrict__ src,
                                               const float* __restrict__ w,
                                               const float* __restrict__ f1,
                                               const float* __restrict__ f2,
                                               u16* __restrict__ out1,
                                               u16* __restrict__ out2) {
    __shared__ float redc[256], redp[256];
    int tid = threadIdx.x;
    size_t i = blockIdx.x;
    size_t ip = ((i & 4095) == 0) ? i : i - 1;
    float xc[4], xp[4];
    float ssc = 0.f, ssp = 0.f;
#pragma unroll
    for (int l = 0; l < 4; ++l) {
        int d = tid + l * 256;
        xc[l] = src[i * 1024 + d];  ssc += xc[l] * xc[l];
        xp[l] = src[ip * 1024 + d]; ssp += xp[l] * xp[l];
    }
    redc[tid] = ssc; redp[tid] = ssp; __syncthreads();
    for (int st = 128; st > 0; st >>= 1) {
        if (tid < st) { redc[tid] += redc[tid + st]; redp[tid] += redp[tid + st]; }
        __syncthreads();
    }
    float ic  = 1.f / (sqrtf(redc[0]) * (1.f / 32.f) + 1e-8f);
    float ipv = 1.f / (sqrtf(redp[0]) * (1.f / 32.f) + 1e-8f);
#pragma unroll
    for (int l = 0; l < 4; ++l) {
        int d = tid + l * 256;
        float wd = w[d];
        float xn = wd * xc[l] * ic;
        float xx = wd * xp[l] * ipv;
        float fa = f1[d], fb = f2[d];
        out1[i * 1024 + d] = f2b(fa * xn + (1.f - fa) * xx);
        out2[i * 1024 + d] = f2b(fb * xn + (1.f - fb) * xx);
    }
}

// ---------------------------------------------------------------------------
// kproj (f64 compute, f32 store in transposed Kt4 layout [b][g][key][4]).
// ---------------------------------------------------------------------------
__global__ __launch_bounds__(256) void kproj(const float* __restrict__ x,
                                             const float* __restrict__ w1,
                                             const float* __restrict__ kw,
                                             const float* __restrict__ kb,
                                             float* __restrict__ Kt4,
                                             float* __restrict__ invn) {
    __shared__ double xk[1024];
    __shared__ double red[256];
    int tid = threadIdx.x;
    size_t j = blockIdx.x;
    double ss = 0.0;
    float xc[4];
#pragma unroll
    for (int l = 0; l < 4; ++l) {
        int d = tid + l * 256;
        xc[l] = x[j * 1024 + d];
        ss += (double)xc[l] * (double)xc[l];
    }
    red[tid] = ss; __syncthreads();
    for (int st = 128; st > 0; st >>= 1) {
        if (tid < st) red[tid] += red[tid + st];
        __syncthreads();
    }
    double inv = 1.0 / (sqrt(red[0]) * (1.0 / 32.0) + 1e-8);
#pragma unroll
    for (int l = 0; l < 4; ++l) {
        int d = tid + l * 256;
        xk[d] = (double)w1[d] * (double)xc[l] * inv;
    }
    __syncthreads();
    int wv = tid >> 6, lane = tid & 63;
    int b = (int)(j >> 12), jj = (int)(j & 4095);
    for (int it = 0; it < 16; ++it) {
        int a = wv * 16 + it;
        const float* kr = kw + (size_t)a * 1024;
        double p = 0.0;
#pragma unroll
        for (int m = 0; m < 16; ++m) p += xk[lane + 64 * m] * (double)kr[lane + 64 * m];
        for (int off = 32; off; off >>= 1) p += __shfl_xor(p, off);
        if (lane == 0)
            Kt4[(((size_t)b * 16 + (a >> 2)) * 4096 + jj) * 4 + (a & 3)] = (float)(p + (double)kb[a]);
    }
    if (tid == 0) invn[j] = (float)inv;
}

// ---------------------------------------------------------------------------
// attn_w: ONE WAVE = ONE BLOCK = one query row (round-2 base: best measured
// 811us). Rounds 4/7 falsified both occupancy theories: Occupancy pinned at
// ~20-21% and VALU-issue time constant ~355us across 64-thr/256-thr, LDS
// 9/17/37KB, wpe(1,2)/(2,4). dur tracks VALU-insts/0.42 -> the lever is
// CUTTING VALU WORK. This round: score inner product via v_pk_fma_f32
// (2 FMA/inst, 4 independent pair-accumulators; K loaded as float2 so pairs
// sit in even-aligned VGPR pairs, zero repacking). Same f32 precision class
// (reassociated sum); selection numerics + exact f64 rescore unchanged.
// sched_barrier(0) fences pin the prefetch-ahead schedule.
// ---------------------------------------------------------------------------
__global__ __attribute__((amdgpu_waves_per_eu(1, 2)))
__launch_bounds__(64) void attn_w(const float* __restrict__ x,
                                  const float* __restrict__ w1,
                                  const float* __restrict__ qwT4,
                                  const float* __restrict__ qb,
                                  const float* __restrict__ Kt4,
                                  const float* __restrict__ invn,
                                  u16* __restrict__ y) {
    __shared__ float  sc[4096];
    __shared__ double qv64s[64];
    __shared__ int    candL[40];
    __shared__ float  pwL[32];
    __shared__ int    idxL[32];

    int lane = threadIdx.x;
    int i = blockIdx.x;
    int b = i >> 12;
    int base = b << 12;

    // ---- Q projection: lane a computes Q[a]; 4 independent f64 accumulators
    const float* xr = x + (size_t)i * 1024;
    double qp0 = 0.0, qp1 = 0.0, qp2 = 0.0, qp3 = 0.0;
#pragma unroll 4
    for (int d4 = 0; d4 < 256; ++d4) {
        float4 w4  = *(const float4*)(w1 + d4 * 4);
        float4 x4  = *(const float4*)(xr + d4 * 4);
        float4 qw4 = *(const float4*)(qwT4 + (size_t)d4 * 256 + lane * 4);
        qp0 += (double)(w4.x * x4.x) * (double)qw4.x;
        qp1 += (double)(w4.y * x4.y) * (double)qw4.y;
        qp2 += (double)(w4.z * x4.z) * (double)qw4.z;
        qp3 += (double)(w4.w * x4.w) * (double)qw4.w;
    }
    double q = ((qp0 + qp1) + (qp2 + qp3)) * (double)invn[i] + (double)qb[lane];
    qv64s[lane] = q;
    float qf = (float)q;

    // broadcast all 64 q values into per-lane f32x2 registers via shuffles
    f32x2 qp2v[32];
#pragma unroll
    for (int g = 0; g < 32; ++g) {
        qp2v[g].x = __shfl(qf, 2 * g + 0);
        qp2v[g].y = __shfl(qf, 2 * g + 1);
    }

    // ---- f32 scores via v_pk_fma_f32, double-buffered 32x f32x2 K batches ----
    // Kt4 as f32x2: element (b,g,key,h) at ((b*16+g)*4096+key)*2 + h,
    // h=0 -> dims(4g,4g+1), h=1 -> dims(4g+2,4g+3). kv[gg] (g=gg>>1,h=gg&1)
    // holds dims (2*gg, 2*gg+1) == qp2v[gg]'s dims.
    const f32x2* K2 = (const f32x2*)Kt4 + (size_t)b * 16 * 8192;
    f32x2 kva[32], kvb[32];
    float lv1 = -3.4e38f, lv2 = -3.4e38f;
    int   li1 = 0x7ffffffe, li2 = 0x7fffffff;
#pragma unroll
    for (int gg = 0; gg < 32; ++gg)
        kva[gg] = K2[(gg >> 1) * 8192 + 2 * lane + (gg & 1)];

#define SCORE_PROC(BUF, JEXPR)                                                  \
    {                                                                           \
        int j_ = (JEXPR);                                                       \
        f32x2 a0 = {0.f, 0.f}, a1 = {0.f, 0.f}, a2 = {0.f, 0.f}, a3 = {0.f, 0.f}; \
        _Pragma("unroll")                                                       \
        for (int gg = 0; gg < 32; gg += 4) {                                    \
            PKFMA(a0, qp2v[gg + 0], BUF[gg + 0]);                               \
            PKFMA(a1, qp2v[gg + 1], BUF[gg + 1]);                               \
            PKFMA(a2, qp2v[gg + 2], BUF[gg + 2]);                               \
            PKFMA(a3, qp2v[gg + 3], BUF[gg + 3]);                               \
        }                                                                       \
        float s_ = ((a0.x + a0.y) + (a1.x + a1.y))                              \
                 + ((a2.x + a2.y) + (a3.x + a3.y));                             \
        s_ *= 0.125f;                                                           \
        if (!(s_ == s_)) s_ = -3.3e38f;                                         \
        sc[j_] = s_;                                                            \
        if (s_ > lv1 || (s_ == lv1 && j_ < li1)) {                              \
            lv2 = lv1; li2 = li1; lv1 = s_; li1 = j_;                           \
        } else if (s_ > lv2 || (s_ == lv2 && j_ < li2)) { lv2 = s_; li2 = j_; } \
    }

#pragma unroll 1
    for (int t = 0; t < 64; t += 2) {
        int j1 = (t + 1) * 64 + lane;
#pragma unroll
        for (int gg = 0; gg < 32; ++gg)
            kvb[gg] = K2[(gg >> 1) * 8192 + 2 * j1 + (gg & 1)];
        __builtin_amdgcn_sched_barrier(0);   // kvb loads stay ABOVE kva compute
        SCORE_PROC(kva, t * 64 + lane);
        __builtin_amdgcn_sched_barrier(0);
        if (t + 2 < 64) {
            int j2 = (t + 2) * 64 + lane;
#pragma unroll
            for (int gg = 0; gg < 32; ++gg)
                kva[gg] = K2[(gg >> 1) * 8192 + 2 * j2 + (gg & 1)];
        }
        __builtin_amdgcn_sched_barrier(0);   // kva loads stay ABOVE kvb compute
        SCORE_PROC(kvb, j1);
        __builtin_amdgcn_sched_barrier(0);
    }
#undef SCORE_PROC

    // ---- stage-1: extract top-40 (shuffle-only; no barriers) ----
    bool v2ok = true;
    for (int it = 0; it < 40; ++it) {
        float mv = lv1; int mi = li1;
#pragma unroll
        for (int off = 32; off >= 1; off >>= 1) {
            float ov = __shfl_xor(mv, off); int oi = __shfl_xor(mi, off);
            if (ov > mv || (ov == mv && oi < mi)) { mv = ov; mi = oi; }
        }
        if (lane == 0) candL[it] = mi;
        if (li1 == mi) {                    // this lane owned the winner
            sc[mi] = -3.4e38f;
            if (v2ok) { lv1 = lv2; li1 = li2; v2ok = false; }
            else {                           // rescan own 64 slots, fresh top-2
                lv1 = -3.4e38f; li1 = 0x7ffffffe; lv2 = -3.4e38f; li2 = 0x7fffffff;
                for (int t = 0; t < 64; ++t) {
                    int j = t * 64 + lane;
                    float v = sc[j];
                    if (v > lv1 || (v == lv1 && j < li1)) { lv2 = lv1; li2 = li1; lv1 = v; li1 = j; }
                    else if (v > lv2 || (v == lv2 && j < li2)) { lv2 = v; li2 = j; }
                }
                v2ok = true;
            }
        }
    }

    // ---- stage-2: f64 rescore of the 40 candidates ----
    const float4* K4 = (const float4*)Kt4 + (size_t)b * 16 * 4096;
    int c = (lane < 40) ? lane : 0;
    int j = candL[c];
    double s = 0.0;
#pragma unroll
    for (int g = 0; g < 16; ++g) {
        float4 kv = K4[g * 4096 + j];
        s += qv64s[4 * g + 0] * (double)kv.x + qv64s[4 * g + 1] * (double)kv.y
           + qv64s[4 * g + 2] * (double)kv.z + qv64s[4 * g + 3] * (double)kv.w;
    }
    s *= 0.125;
    if (lane >= 40) { s = -1.0e300; j = 0x7fffffff; }

    // ---- exact rank among the 40 (tie -> lower key index) ----
    int rank = 0;
    for (int c2 = 0; c2 < 40; ++c2) {
        double s2 = __shfl(s, c2); int j2 = __shfl(j, c2);
        if (s2 > s || (s2 == s && j2 < j)) ++rank;
    }

    // ---- f64 softmax over ranks 0..31 ----
    unsigned long long m0 = __ballot(rank == 0);
    int src = __ffsll((unsigned long long)m0) - 1;
    double mx = __shfl(s, src);
    double e = (rank < 32) ? exp(s - mx) : 0.0;
    double sum = e;
#pragma unroll
    for (int off = 1; off < 64; off <<= 1) sum += __shfl_xor(sum, off);
    if (rank < 32) {
        pwL[rank] = (float)(e / sum) * invn[base + j];
        idxL[rank] = j;
    }

    // ---- gather (double-buffered rows, schedule pinned) ----
    float acc[16], xga[16], xgb[16];
#pragma unroll
    for (int m = 0; m < 16; ++m) acc[m] = 0.f;
    {
        const float* x0 = x + (size_t)(base + idxL[0]) * 1024;
#pragma unroll
        for (int m = 0; m < 16; ++m) xga[m] = x0[m * 64 + lane];
    }
#pragma unroll 1
    for (int k = 0; k < 32; k += 2) {
        const float* xn1 = x + (size_t)(base + idxL[k + 1]) * 1024;
#pragma unroll
        for (int m = 0; m < 16; ++m) xgb[m] = xn1[m * 64 + lane];
        __builtin_amdgcn_sched_barrier(0);
        float p0 = pwL[k];
#pragma unroll
        for (int m = 0; m < 16; ++m) acc[m] += p0 * xga[m];
        __builtin_amdgcn_sched_barrier(0);
        if (k + 2 < 32) {
            const float* xn2 = x + (size_t)(base + idxL[k + 2]) * 1024;
#pragma unroll
            for (int m = 0; m < 16; ++m) xga[m] = xn2[m * 64 + lane];
        }
        __builtin_amdgcn_sched_barrier(0);
        float p1 = pwL[k + 1];
#pragma unroll
        for (int m = 0; m < 16; ++m) acc[m] += p1 * xgb[m];
        __builtin_amdgcn_sched_barrier(0);
    }
#pragma unroll
    for (int m = 0; m < 16; ++m) {
        int d = m * 64 + lane;
        y[(size_t)i * 1024 + d] = f2b(w1[d] * acc[m]);
    }
}

// ---------------------------------------------------------------------------
// MFMA bf16 GEMM: C[M,N] = A[M,K] @ B[N,K]^T. 128x128 tile, BK=64,
// 4 waves (2x2 of 64x64), 16x16x32 MFMA, global_load_lds width-16 staging.
// T1 XCD-aware bijective block swizzle: HW linear id is by*gx+bx, and
// hw%8==bx for gx=8 -> each XCD owned one tile-COLUMN and streamed the whole
// A matrix. Chunked remap gives each XCD gx contiguous row-bands.
// EPI: 0 = bf16(acc + f32 bias[col])
//      1 = bf16(acc + bf16 aux0[g])              (in-place-safe)
//      2 = bf16(sigmoid(acc) * bf16 aux0[g])     (in-place-safe)
//      3 = f32: outF[g] = acc + f32 auxF[g]
//      4 = bf16(sigmoid(acc))
//      5 = bf16(relu(acc)^2)
//      6 = f32: outF[g] += bf16(aux0[g]) * acc   (read-modify-write)
// ---------------------------------------------------------------------------
template <int EPI>
__global__ __launch_bounds__(256) void gemm_bt(const u16* __restrict__ A,
                                               const u16* __restrict__ B,
                                               u16* outB, float* outF,
                                               const float* __restrict__ biasF,
                                               const u16* aux0,
                                               const float* auxF,
                                               int N, int K, int lda, int ldb) {
    __shared__ u16 As[128 * 64];
    __shared__ u16 Bs[128 * 64];
    int tid = threadIdx.x;
    int lane = tid & 63;
    int wv = tid >> 6;

    // T1 XCD swizzle (bijective; all grids here have nwg % 8 == 0)
    int gx = gridDim.x, gy = gridDim.y;
    int nwg = gx * gy;
    int bx = blockIdx.x, by = blockIdx.y;
    if ((nwg & 7) == 0) {
        int hw = by * gx + bx;
        int q = nwg >> 3;
        int lg = (hw & 7) * q + (hw >> 3);
        bx = lg % gx;
        by = lg / gx;
    }

    int row0 = by * 128;
    int col0 = bx * 128;
    int wm = (wv >> 1) * 64;
    int wn = (wv & 1) * 64;
    int frow = lane & 15, quad = lane >> 4;

    float4v zero = {0.f, 0.f, 0.f, 0.f};
    float4v acc[4][4];
#pragma unroll
    for (int i = 0; i < 4; ++i)
#pragma unroll
        for (int j = 0; j < 4; ++j) acc[i][j] = zero;

    for (int k0 = 0; k0 < K; k0 += 64) {
#pragma unroll
        for (int it = 0; it < 4; ++it) {
            int base = (wv * 4 + it) * 512;      // element offset (wave-uniform)
            int e = base + lane * 8;
            int r = e >> 6, c = e & 63;
            GLOAD_LDS16(A + (size_t)(row0 + r) * lda + (k0 + c), &As[base]);
            GLOAD_LDS16(B + (size_t)(col0 + r) * ldb + (k0 + c), &Bs[base]);
        }
        __syncthreads();
#pragma unroll
        for (int kk = 0; kk < 64; kk += 32) {
            short8 a_frag[4], b_frag[4];
#pragma unroll
            for (int mi = 0; mi < 4; ++mi)
                a_frag[mi] = *(const short8*)&As[(wm + mi * 16 + frow) * 64 + kk + quad * 8];
#pragma unroll
            for (int ni = 0; ni < 4; ++ni)
                b_frag[ni] = *(const short8*)&Bs[(wn + ni * 16 + frow) * 64 + kk + quad * 8];
#pragma unroll
            for (int mi = 0; mi < 4; ++mi)
#pragma unroll
                for (int ni = 0; ni < 4; ++ni)
                    acc[mi][ni] = __builtin_amdgcn_mfma_f32_16x16x32_bf16(
                        a_frag[mi], b_frag[ni], acc[mi][ni], 0, 0, 0);
        }
        __syncthreads();
    }

#pragma unroll
    for (int mi = 0; mi < 4; ++mi) {
#pragma unroll
        for (int ni = 0; ni < 4; ++ni) {
#pragma unroll
            for (int r = 0; r < 4; ++r) {
                int row = row0 + wm + mi * 16 + quad * 4 + r;
                int col = col0 + wn + ni * 16 + frow;
                size_t g = (size_t)row * N + col;
                float v = acc[mi][ni][r];
                if constexpr (EPI == 0) {
                    outB[g] = f2b(v + biasF[col]);
                } else if constexpr (EPI == 1) {
                    outB[g] = f2b(v + b2f(aux0[g]));
                } else if constexpr (EPI == 2) {
                    float sg = 1.f / (1.f + expf(-v));
                    outB[g] = f2b(sg * b2f(aux0[g]));
                } else if constexpr (EPI == 3) {
                    outF[g] = v + auxF[g];
                } else if constexpr (EPI == 4) {
                    outB[g] = f2b(1.f / (1.f + expf(-v)));
                } else if constexpr (EPI == 5) {
                    float t = v > 0.f ? v : 0.f;
                    outB[g] = f2b(t * t);
                } else if constexpr (EPI == 6) {
                    outF[g] = outF[g] + b2f(aux0[g]) * v;
                }
            }
        }
    }
}

// ---------------------------------------------------------------------------
extern "C" void kernel_launch(void* const* d_in, const int* in_sizes, int n_in,
                              void* d_out, int out_size, void* d_ws, size_t ws_size,
                              hipStream_t stream) {
    (void)in_sizes; (void)n_in; (void)out_size; (void)ws_size;
    const float* x   = (const float*)d_in[0];
    const float* n1w = (const float*)d_in[1];
    // d_in[2] tm_mix_k, d_in[5] tm_key_w are dead in the reference
    const float* tmv = (const float*)d_in[3];
    const float* tmr = (const float*)d_in[4];
    const float* vw  = (const float*)d_in[6];
    const float* rw  = (const float*)d_in[7];
    const float* ow  = (const float*)d_in[8];
    const float* qw  = (const float*)d_in[9];
    const float* qb  = (const float*)d_in[10];
    const float* skw = (const float*)d_in[11];
    const float* skb = (const float*)d_in[12];
    const float* svw = (const float*)d_in[13];
    const float* svb = (const float*)d_in[14];
    const float* sow = (const float*)d_in[15];
    const float* sob = (const float*)d_in[16];
    const float* n2w = (const float*)d_in[17];
    const float* cmk = (const float*)d_in[18];
    const float* cmr = (const float*)d_in[19];
    const float* ckw = (const float*)d_in[20];
    const float* crw = (const float*)d_in[21];
    const float* cvw = (const float*)d_in[22];

    char* W = (char*)d_ws;
    const size_t MB = 1ull << 20;
    u16*   bufA  = (u16*)(W + 0 * MB);     // 16 MB
    u16*   bufB  = (u16*)(W + 16 * MB);    // 16 MB (with C forms 32 MB k2 chunk)
    u16*   bufC  = (u16*)(W + 32 * MB);    // 16 MB
    u16*   bufD  = (u16*)(W + 48 * MB);    // 16 MB
    float* Kt4   = (float*)(W + 64 * MB);  // 2 MB  [b][g][key][4]
    float* invn  = (float*)(W + 66 * MB);  // 32 KB
    float* qwT4  = (float*)(W + 67 * MB);  // 256 KB
    u16*   ckw16 = (u16*)(W + 68 * MB);    // 8 MB
    u16*   cvw16 = (u16*)(W + 76 * MB);    // 8 MB
    u16*   svw16 = (u16*)(W + 84 * MB);    // 2 MB each below
    u16*   sow16 = (u16*)(W + 86 * MB);
    u16*   vw16  = (u16*)(W + 88 * MB);
    u16*   rw16  = (u16*)(W + 90 * MB);
    u16*   ow16  = (u16*)(W + 92 * MB);
    u16*   crw16 = (u16*)(W + 94 * MB);    // peak 96 MB
    float* x1    = (float*)d_out;          // 32 MB f32, accumulated in place

    dim3 blk(256);
    dim3 gN1024(8, 64);
    dim3 gN2048(16, 64);
    const int NW = 512;

    // weight prep
    wcvt<<<NW, blk, 0, stream>>>(svw, svw16, 1024 * 1024);
    wcvt<<<NW, blk, 0, stream>>>(sow, sow16, 1024 * 1024);
    wcvt<<<NW, blk, 0, stream>>>(vw,  vw16,  1024 * 1024);
    wcvt<<<NW, blk, 0, stream>>>(rw,  rw16,  1024 * 1024);
    wcvt<<<NW, blk, 0, stream>>>(ow,  ow16,  1024 * 1024);
    wcvt<<<NW, blk, 0, stream>>>(crw, crw16, 1024 * 1024);
    wcvt<<<NW, blk, 0, stream>>>(ckw, ckw16, 4096 * 1024);
    wcvt<<<NW, blk, 0, stream>>>(cvw, cvw16, 1024 * 4096);
    prep_qwT4<<<256, blk, 0, stream>>>(qw, qwT4);

    // --- time-mix ---
    mix2out<<<8192, blk, 0, stream>>>(x, n1w, tmv, tmr, bufA, bufC);  // vin, rin
    kproj<<<8192, blk, 0, stream>>>(x, n1w, skw, skb, Kt4, invn);
    attn_w<<<8192, dim3(64), 0, stream>>>(x, n1w, qwT4, qb, Kt4, invn, bufB); // y
    // t = y @ sa_v_w^T + svb
    gemm_bt<0><<<gN1024, blk, 0, stream>>>(bufB, svw16, bufD, nullptr, svb, nullptr, nullptr, 1024, 1024, 1024, 1024);
    // attnO = t @ sa_o_w^T + sob  (overwrites y, dead)
    gemm_bt<0><<<gN1024, blk, 0, stream>>>(bufD, sow16, bufB, nullptr, sob, nullptr, nullptr, 1024, 1024, 1024, 1024);
    // z = vin @ tm_value_w^T + attnO   (in-place over attnO)
    gemm_bt<1><<<gN1024, blk, 0, stream>>>(bufA, vw16, bufB, nullptr, nullptr, bufB, nullptr, 1024, 1024, 1024, 1024);
    // rkv = sigmoid(rin @ tm_recept_w^T) * z   (in-place over z)
    gemm_bt<2><<<gN1024, blk, 0, stream>>>(bufC, rw16, bufB, nullptr, nullptr, bufB, nullptr, 1024, 1024, 1024, 1024);
    // x1 = x + rkv @ tm_out_w^T   (f32, into d_out)
    gemm_bt<3><<<gN1024, blk, 0, stream>>>(bufB, ow16, nullptr, x1, nullptr, nullptr, x, 1024, 1024, 1024, 1024);

    // --- channel-mix ---
    mix2out<<<8192, blk, 0, stream>>>(x1, n2w, cmk, cmr, bufA, bufC);  // kin2, rin2
    // sig2 = sigmoid(rin2 @ cm_recept_w^T) -> D
    gemm_bt<4><<<gN1024, blk, 0, stream>>>(bufC, crw16, bufD, nullptr, nullptr, nullptr, nullptr, 1024, 1024, 1024, 1024);
    // 2 chunks of 2048 DI-columns; k2 chunk (32 MB bf16) spans bufB..bufC
    for (int c = 0; c < 2; ++c) {
        const u16* ckw_c = ckw16 + (size_t)c * 2048 * 1024;  // rows c*2048.. of (4096,1024)
        const u16* cvw_c = cvw16 + (size_t)c * 2048;         // cols c*2048.. of (1024,4096)
        gemm_bt<5><<<gN2048, blk, 0, stream>>>(bufA, ckw_c, bufB, nullptr, nullptr, nullptr, nullptr,
                                               2048, 1024, 1024, 1024);
        gemm_bt<6><<<gN1024, blk, 0, stream>>>(bufB, cvw_c, nullptr, x1, nullptr, bufD, nullptr,
                                               1024, 2048, 2048, 4096);
    }
}

// Round 17
// 1301.201 us; speedup vs baseline: 1.2238x; 1.1707x over previous
//
#include <hip/hip_runtime.h>
#include <math.h>

typedef unsigned short u16;
using short8  = __attribute__((ext_vector_type(8))) short;
using float4v = __attribute__((ext_vector_type(4))) float;

__device__ __forceinline__ float b2f(u16 u) {
    union { unsigned int i; float f; } v; v.i = ((unsigned int)u) << 16; return v.f;
}
__device__ __forceinline__ u16 f2b(float f) {
    union { float f; unsigned int i; } v; v.f = f;
    unsigned int x = v.i;
    unsigned int r = (x + 0x7fffu + ((x >> 16) & 1u)) >> 16;
    return (u16)r;
}

#define GLOAD_LDS16(gp, lp) \
    __builtin_amdgcn_global_load_lds( \
        (const __attribute__((address_space(1))) unsigned int*)(gp), \
        (__attribute__((address_space(3))) unsigned int*)(lp), 16, 0, 0)

// ---------------------------------------------------------------------------
__global__ __launch_bounds__(256) void wcvt(const float* __restrict__ s,
                                            u16* __restrict__ d, int n) {
    int stride = gridDim.x * 256;
    for (int i = blockIdx.x * 256 + threadIdx.x; i < n; i += stride)
        d[i] = f2b(s[i]);
}

// ---------------------------------------------------------------------------
// mix2out: rmsnorm + token-shift mix, TWO mix coefficients in one pass.
// ---------------------------------------------------------------------------
__global__ __launch_bounds__(256) void mix2out(const float* __restrict__ src,
                                               const float* __restrict__ w,
                                               const float* __restrict__ f1,
                                               const float* __restrict__ f2,
                                               u16* __restrict__ out1,
                                               u16* __restrict__ out2) {
    __shared__ float redc[256], redp[256];
    int tid = threadIdx.x;
    size_t i = blockIdx.x;
    size_t ip = ((i & 4095) == 0) ? i : i - 1;
    float xc[4], xp[4];
    float ssc = 0.f, ssp = 0.f;
#pragma unroll
    for (int l = 0; l < 4; ++l) {
        int d = tid + l * 256;
        xc[l] = src[i * 1024 + d];  ssc += xc[l] * xc[l];
        xp[l] = src[ip * 1024 + d]; ssp += xp[l] * xp[l];
    }
    redc[tid] = ssc; redp[tid] = ssp; __syncthreads();
    for (int st = 128; st > 0; st >>= 1) {
        if (tid < st) { redc[tid] += redc[tid + st]; redp[tid] += redp[tid + st]; }
        __syncthreads();
    }
    float ic  = 1.f / (sqrtf(redc[0]) * (1.f / 32.f) + 1e-8f);
    float ipv = 1.f / (sqrtf(redp[0]) * (1.f / 32.f) + 1e-8f);
#pragma unroll
    for (int l = 0; l < 4; ++l) {
        int d = tid + l * 256;
        float wd = w[d];
        float xn = wd * xc[l] * ic;
        float xx = wd * xp[l] * ipv;
        float fa = f1[d], fb = f2[d];
        out1[i * 1024 + d] = f2b(fa * xn + (1.f - fa) * xx);
        out2[i * 1024 + d] = f2b(fb * xn + (1.f - fb) * xx);
    }
}

// ---------------------------------------------------------------------------
// kproj: f64 K projection (Kt4 f32 for rescore) + f64 Q projection
// (qv64 for exact rescore) and split-bf16 hi/lo Q,K for the MFMA score GEMM.
// Split error ~1e-5 rel; score selection downstream uses f16 rounding
// (round-4 validated) so split error is negligible in the 8-candidate margin.
// ---------------------------------------------------------------------------
__global__ __launch_bounds__(256) void kproj(const float* __restrict__ x,
                                             const float* __restrict__ w1,
                                             const float* __restrict__ kw,
                                             const float* __restrict__ kb,
                                             const float* __restrict__ qw,
                                             const float* __restrict__ qb,
                                             float* __restrict__ Kt4,
                                             float* __restrict__ invn,
                                             double* __restrict__ qv64,
                                             u16* __restrict__ Qhi,
                                             u16* __restrict__ Qlo,
                                             u16* __restrict__ Khi,
                                             u16* __restrict__ Klo) {
    __shared__ double xk[1024];
    __shared__ double red[256];
    int tid = threadIdx.x;
    size_t j = blockIdx.x;
    double ss = 0.0;
    float xc[4];
#pragma unroll
    for (int l = 0; l < 4; ++l) {
        int d = tid + l * 256;
        xc[l] = x[j * 1024 + d];
        ss += (double)xc[l] * (double)xc[l];
    }
    red[tid] = ss; __syncthreads();
    for (int st = 128; st > 0; st >>= 1) {
        if (tid < st) red[tid] += red[tid + st];
        __syncthreads();
    }
    double inv = 1.0 / (sqrt(red[0]) * (1.0 / 32.0) + 1e-8);
#pragma unroll
    for (int l = 0; l < 4; ++l) {
        int d = tid + l * 256;
        xk[d] = (double)w1[d] * (double)xc[l] * inv;
    }
    __syncthreads();
    int wv = tid >> 6, lane = tid & 63;
    int b = (int)(j >> 12), jj = (int)(j & 4095);
    for (int it = 0; it < 16; ++it) {
        int a = wv * 16 + it;
        const float* kr = kw + (size_t)a * 1024;
        double p = 0.0;
#pragma unroll
        for (int m = 0; m < 16; ++m) p += xk[lane + 64 * m] * (double)kr[lane + 64 * m];
        for (int off = 32; off; off >>= 1) p += __shfl_xor(p, off);
        if (lane == 0) {
            double kv = p + (double)kb[a];
            Kt4[(((size_t)b * 16 + (a >> 2)) * 4096 + jj) * 4 + (a & 3)] = (float)kv;
            float kf = (float)kv;
            u16 hi = f2b(kf);
            Khi[j * 64 + a] = hi;
            Klo[j * 64 + a] = f2b(kf - b2f(hi));
        }
    }
    for (int it = 0; it < 16; ++it) {
        int a = wv * 16 + it;
        const float* qr = qw + (size_t)a * 1024;
        double p = 0.0;
#pragma unroll
        for (int m = 0; m < 16; ++m) p += xk[lane + 64 * m] * (double)qr[lane + 64 * m];
        for (int off = 32; off; off >>= 1) p += __shfl_xor(p, off);
        if (lane == 0) {
            double qv = p + (double)qb[a];
            qv64[j * 64 + a] = qv;
            float qf = (float)qv;
            u16 hi = f2b(qf);
            Qhi[j * 64 + a] = hi;
            Qlo[j * 64 + a] = f2b(qf - b2f(hi));
        }
    }
    if (tid == 0) invn[j] = (float)inv;
}

// ---------------------------------------------------------------------------
// score_gemm: S[4096q][4096k] = Q @ K^T (per batch), split-bf16 3-term MFMA
// (hi*hi + hi*lo + lo*hi; lo*lo term ~1e-10 dropped). K-dim = 64 = single
// staging step. Output f16 (*0.125) into the 32MB d_out scratch.
// Derived from the validated gemm_bt tile structure.
// ---------------------------------------------------------------------------
__global__ __launch_bounds__(256) void score_gemm(const u16* __restrict__ Qh,
                                                  const u16* __restrict__ Ql,
                                                  const u16* __restrict__ Kh,
                                                  const u16* __restrict__ Kl,
                                                  _Float16* __restrict__ scp) {
    __shared__ u16 Ah[128 * 64], Al[128 * 64], Bh[128 * 64], Bl[128 * 64];
    int tid = threadIdx.x;
    int lane = tid & 63;
    int wv = tid >> 6;
    int row0 = blockIdx.y * 128;
    int col0 = blockIdx.x * 128;
    int frow = lane & 15, quad = lane >> 4;

#pragma unroll
    for (int it = 0; it < 4; ++it) {
        int base = (wv * 4 + it) * 512;
        int e = base + lane * 8;
        int r = e >> 6, c = e & 63;
        GLOAD_LDS16(Qh + (size_t)(row0 + r) * 64 + c, &Ah[base]);
        GLOAD_LDS16(Ql + (size_t)(row0 + r) * 64 + c, &Al[base]);
        GLOAD_LDS16(Kh + (size_t)(col0 + r) * 64 + c, &Bh[base]);
        GLOAD_LDS16(Kl + (size_t)(col0 + r) * 64 + c, &Bl[base]);
    }
    __syncthreads();

    int wm = (wv >> 1) * 64;
    int wn = (wv & 1) * 64;
    float4v zero = {0.f, 0.f, 0.f, 0.f};
    float4v acc[4][4];
#pragma unroll
    for (int i = 0; i < 4; ++i)
#pragma unroll
        for (int j = 0; j < 4; ++j) acc[i][j] = zero;

#pragma unroll
    for (int kk = 0; kk < 64; kk += 32) {
        short8 ah[4], al[4], bh[4], bl[4];
#pragma unroll
        for (int mi = 0; mi < 4; ++mi) {
            ah[mi] = *(const short8*)&Ah[(wm + mi * 16 + frow) * 64 + kk + quad * 8];
            al[mi] = *(const short8*)&Al[(wm + mi * 16 + frow) * 64 + kk + quad * 8];
        }
#pragma unroll
        for (int ni = 0; ni < 4; ++ni) {
            bh[ni] = *(const short8*)&Bh[(wn + ni * 16 + frow) * 64 + kk + quad * 8];
            bl[ni] = *(const short8*)&Bl[(wn + ni * 16 + frow) * 64 + kk + quad * 8];
        }
#pragma unroll
        for (int mi = 0; mi < 4; ++mi)
#pragma unroll
            for (int ni = 0; ni < 4; ++ni) {
                acc[mi][ni] = __builtin_amdgcn_mfma_f32_16x16x32_bf16(ah[mi], bh[ni], acc[mi][ni], 0, 0, 0);
                acc[mi][ni] = __builtin_amdgcn_mfma_f32_16x16x32_bf16(ah[mi], bl[ni], acc[mi][ni], 0, 0, 0);
                acc[mi][ni] = __builtin_amdgcn_mfma_f32_16x16x32_bf16(al[mi], bh[ni], acc[mi][ni], 0, 0, 0);
            }
    }

#pragma unroll
    for (int mi = 0; mi < 4; ++mi)
#pragma unroll
        for (int ni = 0; ni < 4; ++ni)
#pragma unroll
            for (int r = 0; r < 4; ++r) {
                int row = row0 + wm + mi * 16 + quad * 4 + r;
                int col = col0 + wn + ni * 16 + frow;
                scp[(size_t)row * 4096 + col] = (_Float16)(0.125f * acc[mi][ni][r]);
            }
}

// ---------------------------------------------------------------------------
// attn_sel: ONE WAVE = one query row. Scores precomputed by score_gemm (f16
// in scratch): copy the 8KB row to LDS, then run the round-2/4-validated
// selection: per-lane top-2 (j === lane mod 64 ownership), 40x shuffle-max
// extraction with knockout+rescan, exact f64 rescore of 40 candidates
// (qv64 + Kt4 f32), f64 softmax, gather. The 1.25MB-per-wave K/qw score
// stream (the 811us invariant) is GONE.
// ---------------------------------------------------------------------------
__global__ __launch_bounds__(64) void attn_sel(const float* __restrict__ x,
                                               const float* __restrict__ w1,
                                               const _Float16* __restrict__ scp,
                                               const double* __restrict__ qv64,
                                               const float* __restrict__ Kt4,
                                               const float* __restrict__ invn,
                                               u16* __restrict__ y, int bb) {
    __shared__ _Float16 sc[4096];
    __shared__ double qv64s[64];
    __shared__ int    candL[40];
    __shared__ float  pwL[32];
    __shared__ int    idxL[32];

    int lane = threadIdx.x;
    int r = blockIdx.x;
    int i = bb + r;
    int b = i >> 12;
    int base = b << 12;

    qv64s[lane] = qv64[(size_t)i * 64 + lane];

    // copy scores row (f16, 8KB) into LDS: 8 x 16B per lane, linear
    const short8* srow = (const short8*)(scp + (size_t)r * 4096);
#pragma unroll
    for (int t = 0; t < 8; ++t) {
        short8 v = srow[t * 64 + lane];
        *(short8*)&sc[(t * 64 + lane) * 8] = v;
    }

    // per-lane top-2 over own slots (j === lane mod 64)
    float lv1 = -3.4e38f, lv2 = -3.4e38f;
    int   li1 = 0x7ffffffe, li2 = 0x7fffffff;
#pragma unroll 1
    for (int t = 0; t < 64; ++t) {
        int j = t * 64 + lane;
        float v = (float)sc[j];
        if (v > lv1 || (v == lv1 && j < li1)) { lv2 = lv1; li2 = li1; lv1 = v; li1 = j; }
        else if (v > lv2 || (v == lv2 && j < li2)) { lv2 = v; li2 = j; }
    }

    // ---- stage-1: extract top-40 (shuffle-only; no barriers) ----
    bool v2ok = true;
    for (int it = 0; it < 40; ++it) {
        float mv = lv1; int mi = li1;
#pragma unroll
        for (int off = 32; off >= 1; off >>= 1) {
            float ov = __shfl_xor(mv, off); int oi = __shfl_xor(mi, off);
            if (ov > mv || (ov == mv && oi < mi)) { mv = ov; mi = oi; }
        }
        if (lane == 0) candL[it] = mi;
        if (li1 == mi) {                    // this lane owned the winner
            sc[mi] = (_Float16)(-65504.0f);
            if (v2ok) { lv1 = lv2; li1 = li2; v2ok = false; }
            else {                           // rescan own 64 slots, fresh top-2
                lv1 = -3.4e38f; li1 = 0x7ffffffe; lv2 = -3.4e38f; li2 = 0x7fffffff;
                for (int t = 0; t < 64; ++t) {
                    int j = t * 64 + lane;
                    float v = (float)sc[j];
                    if (v > lv1 || (v == lv1 && j < li1)) { lv2 = lv1; li2 = li1; lv1 = v; li1 = j; }
                    else if (v > lv2 || (v == lv2 && j < li2)) { lv2 = v; li2 = j; }
                }
                v2ok = true;
            }
        }
    }

    // ---- stage-2: f64 rescore of the 40 candidates ----
    const float4* K4 = (const float4*)Kt4 + (size_t)b * 16 * 4096;
    int c = (lane < 40) ? lane : 0;
    int j = candL[c];
    double s = 0.0;
#pragma unroll
    for (int g = 0; g < 16; ++g) {
        float4 kv = K4[g * 4096 + j];
        s += qv64s[4 * g + 0] * (double)kv.x + qv64s[4 * g + 1] * (double)kv.y
           + qv64s[4 * g + 2] * (double)kv.z + qv64s[4 * g + 3] * (double)kv.w;
    }
    s *= 0.125;
    if (lane >= 40) { s = -1.0e300; j = 0x7fffffff; }

    // ---- exact rank among the 40 (tie -> lower key index) ----
    int rank = 0;
    for (int c2 = 0; c2 < 40; ++c2) {
        double s2 = __shfl(s, c2); int j2 = __shfl(j, c2);
        if (s2 > s || (s2 == s && j2 < j)) ++rank;
    }

    // ---- f64 softmax over ranks 0..31 ----
    unsigned long long m0 = __ballot(rank == 0);
    int src = __ffsll((unsigned long long)m0) - 1;
    double mx = __shfl(s, src);
    double e = (rank < 32) ? exp(s - mx) : 0.0;
    double sum = e;
#pragma unroll
    for (int off = 1; off < 64; off <<= 1) sum += __shfl_xor(sum, off);
    if (rank < 32) {
        pwL[rank] = (float)(e / sum) * invn[base + j];
        idxL[rank] = j;
    }

    // ---- gather (double-buffered rows, schedule pinned) ----
    float acc[16], xga[16], xgb[16];
#pragma unroll
    for (int m = 0; m < 16; ++m) acc[m] = 0.f;
    {
        const float* x0 = x + (size_t)(base + idxL[0]) * 1024;
#pragma unroll
        for (int m = 0; m < 16; ++m) xga[m] = x0[m * 64 + lane];
    }
#pragma unroll 1
    for (int k = 0; k < 32; k += 2) {
        const float* xn1 = x + (size_t)(base + idxL[k + 1]) * 1024;
#pragma unroll
        for (int m = 0; m < 16; ++m) xgb[m] = xn1[m * 64 + lane];
        __builtin_amdgcn_sched_barrier(0);
        float p0 = pwL[k];
#pragma unroll
        for (int m = 0; m < 16; ++m) acc[m] += p0 * xga[m];
        __builtin_amdgcn_sched_barrier(0);
        if (k + 2 < 32) {
            const float* xn2 = x + (size_t)(base + idxL[k + 2]) * 1024;
#pragma unroll
            for (int m = 0; m < 16; ++m) xga[m] = xn2[m * 64 + lane];
        }
        __builtin_amdgcn_sched_barrier(0);
        float p1 = pwL[k + 1];
#pragma unroll
        for (int m = 0; m < 16; ++m) acc[m] += p1 * xgb[m];
        __builtin_amdgcn_sched_barrier(0);
    }
#pragma unroll
    for (int m = 0; m < 16; ++m) {
        int d = m * 64 + lane;
        y[(size_t)i * 1024 + d] = f2b(w1[d] * acc[m]);
    }
}

// ---------------------------------------------------------------------------
// MFMA bf16 GEMM: C[M,N] = A[M,K] @ B[N,K]^T. 128x128 tile, BK=64,
// 4 waves (2x2 of 64x64), 16x16x32 MFMA, global_load_lds width-16 staging.
// T1 XCD-aware bijective block swizzle.
// EPI: 0 = bf16(acc + f32 bias[col])
//      1 = bf16(acc + bf16 aux0[g])              (in-place-safe)
//      2 = bf16(sigmoid(acc) * bf16 aux0[g])     (in-place-safe)
//      3 = f32: outF[g] = acc + f32 auxF[g]
//      4 = bf16(sigmoid(acc))
//      5 = bf16(relu(acc)^2)
//      6 = f32: outF[g] += bf16(aux0[g]) * acc   (read-modify-write)
// ---------------------------------------------------------------------------
template <int EPI>
__global__ __launch_bounds__(256) void gemm_bt(const u16* __restrict__ A,
                                               const u16* __restrict__ B,
                                               u16* outB, float* outF,
                                               const float* __restrict__ biasF,
                                               const u16* aux0,
                                               const float* auxF,
                                               int N, int K, int lda, int ldb) {
    __shared__ u16 As[128 * 64];
    __shared__ u16 Bs[128 * 64];
    int tid = threadIdx.x;
    int lane = tid & 63;
    int wv = tid >> 6;

    // T1 XCD swizzle (bijective; all grids here have nwg % 8 == 0)
    int gx = gridDim.x, gy = gridDim.y;
    int nwg = gx * gy;
    int bx = blockIdx.x, by = blockIdx.y;
    if ((nwg & 7) == 0) {
        int hw = by * gx + bx;
        int q = nwg >> 3;
        int lg = (hw & 7) * q + (hw >> 3);
        bx = lg % gx;
        by = lg / gx;
    }

    int row0 = by * 128;
    int col0 = bx * 128;
    int wm = (wv >> 1) * 64;
    int wn = (wv & 1) * 64;
    int frow = lane & 15, quad = lane >> 4;

    float4v zero = {0.f, 0.f, 0.f, 0.f};
    float4v acc[4][4];
#pragma unroll
    for (int i = 0; i < 4; ++i)
#pragma unroll
        for (int j = 0; j < 4; ++j) acc[i][j] = zero;

    for (int k0 = 0; k0 < K; k0 += 64) {
#pragma unroll
        for (int it = 0; it < 4; ++it) {
            int base = (wv * 4 + it) * 512;      // element offset (wave-uniform)
            int e = base + lane * 8;
            int r = e >> 6, c = e & 63;
            GLOAD_LDS16(A + (size_t)(row0 + r) * lda + (k0 + c), &As[base]);
            GLOAD_LDS16(B + (size_t)(col0 + r) * ldb + (k0 + c), &Bs[base]);
        }
        __syncthreads();
#pragma unroll
        for (int kk = 0; kk < 64; kk += 32) {
            short8 a_frag[4], b_frag[4];
#pragma unroll
            for (int mi = 0; mi < 4; ++mi)
                a_frag[mi] = *(const short8*)&As[(wm + mi * 16 + frow) * 64 + kk + quad * 8];
#pragma unroll
            for (int ni = 0; ni < 4; ++ni)
                b_frag[ni] = *(const short8*)&Bs[(wn + ni * 16 + frow) * 64 + kk + quad * 8];
#pragma unroll
            for (int mi = 0; mi < 4; ++mi)
#pragma unroll
                for (int ni = 0; ni < 4; ++ni)
                    acc[mi][ni] = __builtin_amdgcn_mfma_f32_16x16x32_bf16(
                        a_frag[mi], b_frag[ni], acc[mi][ni], 0, 0, 0);
        }
        __syncthreads();
    }

#pragma unroll
    for (int mi = 0; mi < 4; ++mi) {
#pragma unroll
        for (int ni = 0; ni < 4; ++ni) {
#pragma unroll
            for (int r = 0; r < 4; ++r) {
                int row = row0 + wm + mi * 16 + quad * 4 + r;
                int col = col0 + wn + ni * 16 + frow;
                size_t g = (size_t)row * N + col;
                float v = acc[mi][ni][r];
                if constexpr (EPI == 0) {
                    outB[g] = f2b(v + biasF[col]);
                } else if constexpr (EPI == 1) {
                    outB[g] = f2b(v + b2f(aux0[g]));
                } else if constexpr (EPI == 2) {
                    float sg = 1.f / (1.f + expf(-v));
                    outB[g] = f2b(sg * b2f(aux0[g]));
                } else if constexpr (EPI == 3) {
                    outF[g] = v + auxF[g];
                } else if constexpr (EPI == 4) {
                    outB[g] = f2b(1.f / (1.f + expf(-v)));
                } else if constexpr (EPI == 5) {
                    float t = v > 0.f ? v : 0.f;
                    outB[g] = f2b(t * t);
                } else if constexpr (EPI == 6) {
                    outF[g] = outF[g] + b2f(aux0[g]) * v;
                }
            }
        }
    }
}

// ---------------------------------------------------------------------------
extern "C" void kernel_launch(void* const* d_in, const int* in_sizes, int n_in,
                              void* d_out, int out_size, void* d_ws, size_t ws_size,
                              hipStream_t stream) {
    (void)in_sizes; (void)n_in; (void)out_size; (void)ws_size;
    const float* x   = (const float*)d_in[0];
    const float* n1w = (const float*)d_in[1];
    // d_in[2] tm_mix_k, d_in[5] tm_key_w are dead in the reference
    const float* tmv = (const float*)d_in[3];
    const float* tmr = (const float*)d_in[4];
    const float* vw  = (const float*)d_in[6];
    const float* rw  = (const float*)d_in[7];
    const float* ow  = (const float*)d_in[8];
    const float* qw  = (const float*)d_in[9];
    const float* qb  = (const float*)d_in[10];
    const float* skw = (const float*)d_in[11];
    const float* skb = (const float*)d_in[12];
    const float* svw = (const float*)d_in[13];
    const float* svb = (const float*)d_in[14];
    const float* sow = (const float*)d_in[15];
    const float* sob = (const float*)d_in[16];
    const float* n2w = (const float*)d_in[17];
    const float* cmk = (const float*)d_in[18];
    const float* cmr = (const float*)d_in[19];
    const float* ckw = (const float*)d_in[20];
    const float* crw = (const float*)d_in[21];
    const float* cvw = (const float*)d_in[22];

    char* W = (char*)d_ws;
    const size_t MB = 1ull << 20;
    u16*   bufA  = (u16*)(W + 0 * MB);     // 16 MB
    u16*   bufB  = (u16*)(W + 16 * MB);    // 16 MB (with C forms 32 MB k2 chunk)
    u16*   bufC  = (u16*)(W + 32 * MB);    // 16 MB
    u16*   bufD  = (u16*)(W + 48 * MB);    // 16 MB (scratch below until 1st gemm)
    // attn scratch INSIDE bufD's slot (freed before bufD's first write):
    double* qv64 = (double*)(W + 48 * MB); // 4 MB  [8192][64] f64
    u16*   Qhi   = (u16*)(W + 52 * MB);    // 1 MB
    u16*   Qlo   = (u16*)(W + 53 * MB);    // 1 MB
    u16*   Khi   = (u16*)(W + 54 * MB);    // 1 MB
    u16*   Klo   = (u16*)(W + 55 * MB);    // 1 MB
    float* Kt4   = (float*)(W + 64 * MB);  // 2 MB  [b][g][key][4]
    float* invn  = (float*)(W + 66 * MB);  // 32 KB
    u16*   ckw16 = (u16*)(W + 68 * MB);    // 8 MB
    u16*   cvw16 = (u16*)(W + 76 * MB);    // 8 MB
    u16*   svw16 = (u16*)(W + 84 * MB);    // 2 MB each below
    u16*   sow16 = (u16*)(W + 86 * MB);
    u16*   vw16  = (u16*)(W + 88 * MB);
    u16*   rw16  = (u16*)(W + 90 * MB);
    u16*   ow16  = (u16*)(W + 92 * MB);
    u16*   crw16 = (u16*)(W + 94 * MB);    // peak 96 MB
    float* x1    = (float*)d_out;          // 32 MB f32, accumulated in place
    _Float16* scF = (_Float16*)d_out;      // scores scratch (32 MB) BEFORE x1 use

    dim3 blk(256);
    dim3 gN1024(8, 64);
    dim3 gN2048(16, 64);
    const int NW = 512;

    // weight prep
    wcvt<<<NW, blk, 0, stream>>>(svw, svw16, 1024 * 1024);
    wcvt<<<NW, blk, 0, stream>>>(sow, sow16, 1024 * 1024);
    wcvt<<<NW, blk, 0, stream>>>(vw,  vw16,  1024 * 1024);
    wcvt<<<NW, blk, 0, stream>>>(rw,  rw16,  1024 * 1024);
    wcvt<<<NW, blk, 0, stream>>>(ow,  ow16,  1024 * 1024);
    wcvt<<<NW, blk, 0, stream>>>(crw, crw16, 1024 * 1024);
    wcvt<<<NW, blk, 0, stream>>>(ckw, ckw16, 4096 * 1024);
    wcvt<<<NW, blk, 0, stream>>>(cvw, cvw16, 1024 * 4096);

    // --- time-mix ---
    mix2out<<<8192, blk, 0, stream>>>(x, n1w, tmv, tmr, bufA, bufC);  // vin, rin
    kproj<<<8192, blk, 0, stream>>>(x, n1w, skw, skb, qw, qb, Kt4, invn,
                                    qv64, Qhi, Qlo, Khi, Klo);
    for (int bb = 0; bb < 2; ++bb) {
        size_t o = (size_t)bb * 4096 * 64;
        score_gemm<<<dim3(32, 32), blk, 0, stream>>>(Qhi + o, Qlo + o,
                                                     Khi + o, Klo + o, scF);
        attn_sel<<<4096, dim3(64), 0, stream>>>(x, n1w, scF, qv64, Kt4, invn,
                                                bufB, bb * 4096);
    }
    // t = y @ sa_v_w^T + svb
    gemm_bt<0><<<gN1024, blk, 0, stream>>>(bufB, svw16, bufD, nullptr, svb, nullptr, nullptr, 1024, 1024, 1024, 1024);
    // attnO = t @ sa_o_w^T + sob  (overwrites y, dead)
    gemm_bt<0><<<gN1024, blk, 0, stream>>>(bufD, sow16, bufB, nullptr, sob, nullptr, nullptr, 1024, 1024, 1024, 1024);
    // z = vin @ tm_value_w^T + attnO   (in-place over attnO)
    gemm_bt<1><<<gN1024, blk, 0, stream>>>(bufA, vw16, bufB, nullptr, nullptr, bufB, nullptr, 1024, 1024, 1024, 1024);
    // rkv = sigmoid(rin @ tm_recept_w^T) * z   (in-place over z)
    gemm_bt<2><<<gN1024, blk, 0, stream>>>(bufC, rw16, bufB, nullptr, nullptr, bufB, nullptr, 1024, 1024, 1024, 1024);
    // x1 = x + rkv @ tm_out_w^T   (f32, into d_out — scores scratch is dead now)
    gemm_bt<3><<<gN1024, blk, 0, stream>>>(bufB, ow16, nullptr, x1, nullptr, nullptr, x, 1024, 1024, 1024, 1024);

    // --- channel-mix ---
    mix2out<<<8192, blk, 0, stream>>>(x1, n2w, cmk, cmr, bufA, bufC);  // kin2, rin2
    // sig2 = sigmoid(rin2 @ cm_recept_w^T) -> D
    gemm_bt<4><<<gN1024, blk, 0, stream>>>(bufC, crw16, bufD, nullptr, nullptr, nullptr, nullptr, 1024, 1024, 1024, 1024);
    // 2 chunks of 2048 DI-columns; k2 chunk (32 MB bf16) spans bufB..bufC
    for (int c = 0; c < 2; ++c) {
        const u16* ckw_c = ckw16 + (size_t)c * 2048 * 1024;  // rows c*2048.. of (4096,1024)
        const u16* cvw_c = cvw16 + (size_t)c * 2048;         // cols c*2048.. of (1024,4096)
        gemm_bt<5><<<gN2048, blk, 0, stream>>>(bufA, ckw_c, bufB, nullptr, nullptr, nullptr, nullptr,
                                               2048, 1024, 1024, 1024);
        gemm_bt<6><<<gN1024, blk, 0, stream>>>(bufB, cvw_c, nullptr, x1, nullptr, bufD, nullptr,
                                               1024, 2048, 2048, 4096);
    }
}

// Round 18
// 1272.981 us; speedup vs baseline: 1.2510x; 1.0222x over previous
//
#include <hip/hip_runtime.h>
#include <math.h>

typedef unsigned short u16;
using short8  = __attribute__((ext_vector_type(8))) short;
using float4v = __attribute__((ext_vector_type(4))) float;

__device__ __forceinline__ float b2f(u16 u) {
    union { unsigned int i; float f; } v; v.i = ((unsigned int)u) << 16; return v.f;
}
__device__ __forceinline__ u16 f2b(float f) {
    union { float f; unsigned int i; } v; v.f = f;
    unsigned int x = v.i;
    unsigned int r = (x + 0x7fffu + ((x >> 16) & 1u)) >> 16;
    return (u16)r;
}

#define GLOAD_LDS16(gp, lp) \
    __builtin_amdgcn_global_load_lds( \
        (const __attribute__((address_space(1))) unsigned int*)(gp), \
        (__attribute__((address_space(3))) unsigned int*)(lp), 16, 0, 0)

// ---------------------------------------------------------------------------
__global__ __launch_bounds__(256) void wcvt(const float* __restrict__ s,
                                            u16* __restrict__ d, int n) {
    int stride = gridDim.x * 256;
    for (int i = blockIdx.x * 256 + threadIdx.x; i < n; i += stride)
        d[i] = f2b(s[i]);
}

// ---------------------------------------------------------------------------
// mix2out: rmsnorm + token-shift mix, TWO mix coefficients in one pass.
// ---------------------------------------------------------------------------
__global__ __launch_bounds__(256) void mix2out(const float* __restrict__ src,
                                               const float* __restrict__ w,
                                               const float* __restrict__ f1,
                                               const float* __restrict__ f2,
                                               u16* __restrict__ out1,
                                               u16* __restrict__ out2) {
    __shared__ float redc[256], redp[256];
    int tid = threadIdx.x;
    size_t i = blockIdx.x;
    size_t ip = ((i & 4095) == 0) ? i : i - 1;
    float xc[4], xp[4];
    float ssc = 0.f, ssp = 0.f;
#pragma unroll
    for (int l = 0; l < 4; ++l) {
        int d = tid + l * 256;
        xc[l] = src[i * 1024 + d];  ssc += xc[l] * xc[l];
        xp[l] = src[ip * 1024 + d]; ssp += xp[l] * xp[l];
    }
    redc[tid] = ssc; redp[tid] = ssp; __syncthreads();
    for (int st = 128; st > 0; st >>= 1) {
        if (tid < st) { redc[tid] += redc[tid + st]; redp[tid] += redp[tid + st]; }
        __syncthreads();
    }
    float ic  = 1.f / (sqrtf(redc[0]) * (1.f / 32.f) + 1e-8f);
    float ipv = 1.f / (sqrtf(redp[0]) * (1.f / 32.f) + 1e-8f);
#pragma unroll
    for (int l = 0; l < 4; ++l) {
        int d = tid + l * 256;
        float wd = w[d];
        float xn = wd * xc[l] * ic;
        float xx = wd * xp[l] * ipv;
        float fa = f1[d], fb = f2[d];
        out1[i * 1024 + d] = f2b(fa * xn + (1.f - fa) * xx);
        out2[i * 1024 + d] = f2b(fb * xn + (1.f - fb) * xx);
    }
}

// ---------------------------------------------------------------------------
// kproj: f64 K projection (Kt4 f32 for rescore) + f64 Q projection
// (qv64 for exact rescore) and split-bf16 hi/lo Q,K for the MFMA score GEMM.
// Round-18: 4-wide ILP on the dot loops (rocprof: 238us, VALUBusy 48% ->
// serial 16-FMA f64 chains + 6-step shuffle reduces, no overlap). Four
// accumulators interleave 4 independent chains; xk LDS reads amortized 4x.
// BIT-IDENTICAL per-output math (same FMA order, same reduction tree).
// ---------------------------------------------------------------------------
__global__ __launch_bounds__(256) void kproj(const float* __restrict__ x,
                                             const float* __restrict__ w1,
                                             const float* __restrict__ kw,
                                             const float* __restrict__ kb,
                                             const float* __restrict__ qw,
                                             const float* __restrict__ qb,
                                             float* __restrict__ Kt4,
                                             float* __restrict__ invn,
                                             double* __restrict__ qv64,
                                             u16* __restrict__ Qhi,
                                             u16* __restrict__ Qlo,
                                             u16* __restrict__ Khi,
                                             u16* __restrict__ Klo) {
    __shared__ double xk[1024];
    __shared__ double red[256];
    int tid = threadIdx.x;
    size_t j = blockIdx.x;
    double ss = 0.0;
    float xc[4];
#pragma unroll
    for (int l = 0; l < 4; ++l) {
        int d = tid + l * 256;
        xc[l] = x[j * 1024 + d];
        ss += (double)xc[l] * (double)xc[l];
    }
    red[tid] = ss; __syncthreads();
    for (int st = 128; st > 0; st >>= 1) {
        if (tid < st) red[tid] += red[tid + st];
        __syncthreads();
    }
    double inv = 1.0 / (sqrt(red[0]) * (1.0 / 32.0) + 1e-8);
#pragma unroll
    for (int l = 0; l < 4; ++l) {
        int d = tid + l * 256;
        xk[d] = (double)w1[d] * (double)xc[l] * inv;
    }
    __syncthreads();
    int wv = tid >> 6, lane = tid & 63;
    int b = (int)(j >> 12), jj = (int)(j & 4095);
    for (int it = 0; it < 16; it += 4) {
        int a0 = wv * 16 + it;
        const float* kr0 = kw + (size_t)(a0 + 0) * 1024;
        const float* kr1 = kw + (size_t)(a0 + 1) * 1024;
        const float* kr2 = kw + (size_t)(a0 + 2) * 1024;
        const float* kr3 = kw + (size_t)(a0 + 3) * 1024;
        double p0 = 0.0, p1 = 0.0, p2 = 0.0, p3 = 0.0;
#pragma unroll
        for (int m = 0; m < 16; ++m) {
            int d = lane + 64 * m;
            double xv = xk[d];
            p0 += xv * (double)kr0[d];
            p1 += xv * (double)kr1[d];
            p2 += xv * (double)kr2[d];
            p3 += xv * (double)kr3[d];
        }
#pragma unroll
        for (int off = 32; off; off >>= 1) {
            p0 += __shfl_xor(p0, off);
            p1 += __shfl_xor(p1, off);
            p2 += __shfl_xor(p2, off);
            p3 += __shfl_xor(p3, off);
        }
        if (lane == 0) {
            double pv[4] = {p0, p1, p2, p3};
#pragma unroll
            for (int u = 0; u < 4; ++u) {
                int a = a0 + u;
                double kv = pv[u] + (double)kb[a];
                Kt4[(((size_t)b * 16 + (a >> 2)) * 4096 + jj) * 4 + (a & 3)] = (float)kv;
                float kf = (float)kv;
                u16 hi = f2b(kf);
                Khi[j * 64 + a] = hi;
                Klo[j * 64 + a] = f2b(kf - b2f(hi));
            }
        }
    }
    for (int it = 0; it < 16; it += 4) {
        int a0 = wv * 16 + it;
        const float* qr0 = qw + (size_t)(a0 + 0) * 1024;
        const float* qr1 = qw + (size_t)(a0 + 1) * 1024;
        const float* qr2 = qw + (size_t)(a0 + 2) * 1024;
        const float* qr3 = qw + (size_t)(a0 + 3) * 1024;
        double p0 = 0.0, p1 = 0.0, p2 = 0.0, p3 = 0.0;
#pragma unroll
        for (int m = 0; m < 16; ++m) {
            int d = lane + 64 * m;
            double xv = xk[d];
            p0 += xv * (double)qr0[d];
            p1 += xv * (double)qr1[d];
            p2 += xv * (double)qr2[d];
            p3 += xv * (double)qr3[d];
        }
#pragma unroll
        for (int off = 32; off; off >>= 1) {
            p0 += __shfl_xor(p0, off);
            p1 += __shfl_xor(p1, off);
            p2 += __shfl_xor(p2, off);
            p3 += __shfl_xor(p3, off);
        }
        if (lane == 0) {
            double pv[4] = {p0, p1, p2, p3};
#pragma unroll
            for (int u = 0; u < 4; ++u) {
                int a = a0 + u;
                double qv = pv[u] + (double)qb[a];
                qv64[j * 64 + a] = qv;
                float qf = (float)qv;
                u16 hi = f2b(qf);
                Qhi[j * 64 + a] = hi;
                Qlo[j * 64 + a] = f2b(qf - b2f(hi));
            }
        }
    }
    if (tid == 0) invn[j] = (float)inv;
}

// ---------------------------------------------------------------------------
// score_gemm: S[4096q][4096k] = Q @ K^T (per batch), split-bf16 3-term MFMA
// (hi*hi + hi*lo + lo*hi; lo*lo term ~1e-10 dropped). K-dim = 64 = single
// staging step. Output f16 (*0.125) into the 32MB d_out scratch.
// ---------------------------------------------------------------------------
__global__ __launch_bounds__(256) void score_gemm(const u16* __restrict__ Qh,
                                                  const u16* __restrict__ Ql,
                                                  const u16* __restrict__ Kh,
                                                  const u16* __restrict__ Kl,
                                                  _Float16* __restrict__ scp) {
    __shared__ u16 Ah[128 * 64], Al[128 * 64], Bh[128 * 64], Bl[128 * 64];
    int tid = threadIdx.x;
    int lane = tid & 63;
    int wv = tid >> 6;
    int row0 = blockIdx.y * 128;
    int col0 = blockIdx.x * 128;
    int frow = lane & 15, quad = lane >> 4;

#pragma unroll
    for (int it = 0; it < 4; ++it) {
        int base = (wv * 4 + it) * 512;
        int e = base + lane * 8;
        int r = e >> 6, c = e & 63;
        GLOAD_LDS16(Qh + (size_t)(row0 + r) * 64 + c, &Ah[base]);
        GLOAD_LDS16(Ql + (size_t)(row0 + r) * 64 + c, &Al[base]);
        GLOAD_LDS16(Kh + (size_t)(col0 + r) * 64 + c, &Bh[base]);
        GLOAD_LDS16(Kl + (size_t)(col0 + r) * 64 + c, &Bl[base]);
    }
    __syncthreads();

    int wm = (wv >> 1) * 64;
    int wn = (wv & 1) * 64;
    float4v zero = {0.f, 0.f, 0.f, 0.f};
    float4v acc[4][4];
#pragma unroll
    for (int i = 0; i < 4; ++i)
#pragma unroll
        for (int j = 0; j < 4; ++j) acc[i][j] = zero;

#pragma unroll
    for (int kk = 0; kk < 64; kk += 32) {
        short8 ah[4], al[4], bh[4], bl[4];
#pragma unroll
        for (int mi = 0; mi < 4; ++mi) {
            ah[mi] = *(const short8*)&Ah[(wm + mi * 16 + frow) * 64 + kk + quad * 8];
            al[mi] = *(const short8*)&Al[(wm + mi * 16 + frow) * 64 + kk + quad * 8];
        }
#pragma unroll
        for (int ni = 0; ni < 4; ++ni) {
            bh[ni] = *(const short8*)&Bh[(wn + ni * 16 + frow) * 64 + kk + quad * 8];
            bl[ni] = *(const short8*)&Bl[(wn + ni * 16 + frow) * 64 + kk + quad * 8];
        }
#pragma unroll
        for (int mi = 0; mi < 4; ++mi)
#pragma unroll
            for (int ni = 0; ni < 4; ++ni) {
                acc[mi][ni] = __builtin_amdgcn_mfma_f32_16x16x32_bf16(ah[mi], bh[ni], acc[mi][ni], 0, 0, 0);
                acc[mi][ni] = __builtin_amdgcn_mfma_f32_16x16x32_bf16(ah[mi], bl[ni], acc[mi][ni], 0, 0, 0);
                acc[mi][ni] = __builtin_amdgcn_mfma_f32_16x16x32_bf16(al[mi], bh[ni], acc[mi][ni], 0, 0, 0);
            }
    }

#pragma unroll
    for (int mi = 0; mi < 4; ++mi)
#pragma unroll
        for (int ni = 0; ni < 4; ++ni)
#pragma unroll
            for (int r = 0; r < 4; ++r) {
                int row = row0 + wm + mi * 16 + quad * 4 + r;
                int col = col0 + wn + ni * 16 + frow;
                scp[(size_t)row * 4096 + col] = (_Float16)(0.125f * acc[mi][ni][r]);
            }
}

// ---------------------------------------------------------------------------
// attn_sel: ONE WAVE = one query row. Scores precomputed by score_gemm (f16
// in scratch): copy the 8KB row to LDS, then the validated selection:
// per-lane top-2, 40x shuffle-max extraction with knockout+rescan, exact
// f64 rescore of 40 candidates (qv64 + Kt4 f32), f64 softmax, gather.
// ---------------------------------------------------------------------------
__global__ __launch_bounds__(64) void attn_sel(const float* __restrict__ x,
                                               const float* __restrict__ w1,
                                               const _Float16* __restrict__ scp,
                                               const double* __restrict__ qv64,
                                               const float* __restrict__ Kt4,
                                               const float* __restrict__ invn,
                                               u16* __restrict__ y, int bb) {
    __shared__ _Float16 sc[4096];
    __shared__ double qv64s[64];
    __shared__ int    candL[40];
    __shared__ float  pwL[32];
    __shared__ int    idxL[32];

    int lane = threadIdx.x;
    int r = blockIdx.x;
    int i = bb + r;
    int b = i >> 12;
    int base = b << 12;

    qv64s[lane] = qv64[(size_t)i * 64 + lane];

    // copy scores row (f16, 8KB) into LDS: 8 x 16B per lane, linear
    const short8* srow = (const short8*)(scp + (size_t)r * 4096);
#pragma unroll
    for (int t = 0; t < 8; ++t) {
        short8 v = srow[t * 64 + lane];
        *(short8*)&sc[(t * 64 + lane) * 8] = v;
    }

    // per-lane top-2 over own slots (j === lane mod 64)
    float lv1 = -3.4e38f, lv2 = -3.4e38f;
    int   li1 = 0x7ffffffe, li2 = 0x7fffffff;
#pragma unroll 1
    for (int t = 0; t < 64; ++t) {
        int j = t * 64 + lane;
        float v = (float)sc[j];
        if (v > lv1 || (v == lv1 && j < li1)) { lv2 = lv1; li2 = li1; lv1 = v; li1 = j; }
        else if (v > lv2 || (v == lv2 && j < li2)) { lv2 = v; li2 = j; }
    }

    // ---- stage-1: extract top-40 (shuffle-only; no barriers) ----
    bool v2ok = true;
    for (int it = 0; it < 40; ++it) {
        float mv = lv1; int mi = li1;
#pragma unroll
        for (int off = 32; off >= 1; off >>= 1) {
            float ov = __shfl_xor(mv, off); int oi = __shfl_xor(mi, off);
            if (ov > mv || (ov == mv && oi < mi)) { mv = ov; mi = oi; }
        }
        if (lane == 0) candL[it] = mi;
        if (li1 == mi) {                    // this lane owned the winner
            sc[mi] = (_Float16)(-65504.0f);
            if (v2ok) { lv1 = lv2; li1 = li2; v2ok = false; }
            else {                           // rescan own 64 slots, fresh top-2
                lv1 = -3.4e38f; li1 = 0x7ffffffe; lv2 = -3.4e38f; li2 = 0x7fffffff;
                for (int t = 0; t < 64; ++t) {
                    int j = t * 64 + lane;
                    float v = (float)sc[j];
                    if (v > lv1 || (v == lv1 && j < li1)) { lv2 = lv1; li2 = li1; lv1 = v; li1 = j; }
                    else if (v > lv2 || (v == lv2 && j < li2)) { lv2 = v; li2 = j; }
                }
                v2ok = true;
            }
        }
    }

    // ---- stage-2: f64 rescore of the 40 candidates ----
    const float4* K4 = (const float4*)Kt4 + (size_t)b * 16 * 4096;
    int c = (lane < 40) ? lane : 0;
    int j = candL[c];
    double s = 0.0;
#pragma unroll
    for (int g = 0; g < 16; ++g) {
        float4 kv = K4[g * 4096 + j];
        s += qv64s[4 * g + 0] * (double)kv.x + qv64s[4 * g + 1] * (double)kv.y
           + qv64s[4 * g + 2] * (double)kv.z + qv64s[4 * g + 3] * (double)kv.w;
    }
    s *= 0.125;
    if (lane >= 40) { s = -1.0e300; j = 0x7fffffff; }

    // ---- exact rank among the 40 (tie -> lower key index) ----
    int rank = 0;
    for (int c2 = 0; c2 < 40; ++c2) {
        double s2 = __shfl(s, c2); int j2 = __shfl(j, c2);
        if (s2 > s || (s2 == s && j2 < j)) ++rank;
    }

    // ---- f64 softmax over ranks 0..31 ----
    unsigned long long m0 = __ballot(rank == 0);
    int src = __ffsll((unsigned long long)m0) - 1;
    double mx = __shfl(s, src);
    double e = (rank < 32) ? exp(s - mx) : 0.0;
    double sum = e;
#pragma unroll
    for (int off = 1; off < 64; off <<= 1) sum += __shfl_xor(sum, off);
    if (rank < 32) {
        pwL[rank] = (float)(e / sum) * invn[base + j];
        idxL[rank] = j;
    }

    // ---- gather (double-buffered rows, schedule pinned) ----
    float acc[16], xga[16], xgb[16];
#pragma unroll
    for (int m = 0; m < 16; ++m) acc[m] = 0.f;
    {
        const float* x0 = x + (size_t)(base + idxL[0]) * 1024;
#pragma unroll
        for (int m = 0; m < 16; ++m) xga[m] = x0[m * 64 + lane];
    }
#pragma unroll 1
    for (int k = 0; k < 32; k += 2) {
        const float* xn1 = x + (size_t)(base + idxL[k + 1]) * 1024;
#pragma unroll
        for (int m = 0; m < 16; ++m) xgb[m] = xn1[m * 64 + lane];
        __builtin_amdgcn_sched_barrier(0);
        float p0 = pwL[k];
#pragma unroll
        for (int m = 0; m < 16; ++m) acc[m] += p0 * xga[m];
        __builtin_amdgcn_sched_barrier(0);
        if (k + 2 < 32) {
            const float* xn2 = x + (size_t)(base + idxL[k + 2]) * 1024;
#pragma unroll
            for (int m = 0; m < 16; ++m) xga[m] = xn2[m * 64 + lane];
        }
        __builtin_amdgcn_sched_barrier(0);
        float p1 = pwL[k + 1];
#pragma unroll
        for (int m = 0; m < 16; ++m) acc[m] += p1 * xgb[m];
        __builtin_amdgcn_sched_barrier(0);
    }
#pragma unroll
    for (int m = 0; m < 16; ++m) {
        int d = m * 64 + lane;
        y[(size_t)i * 1024 + d] = f2b(w1[d] * acc[m]);
    }
}

// ---------------------------------------------------------------------------
// MFMA bf16 GEMM: C[M,N] = A[M,K] @ B[N,K]^T. 128x128 tile, BK=64,
// 4 waves (2x2 of 64x64), 16x16x32 MFMA, global_load_lds width-16 staging.
// T1 XCD-aware bijective block swizzle.
// EPI: 0 = bf16(acc + f32 bias[col])
//      1 = bf16(acc + bf16 aux0[g])              (in-place-safe)
//      2 = bf16(sigmoid(acc) * bf16 aux0[g])     (in-place-safe)
//      3 = f32: outF[g] = acc + f32 auxF[g]
//      4 = bf16(sigmoid(acc))
//      5 = bf16(relu(acc)^2)
//      6 = f32: outF[g] += bf16(aux0[g]) * acc   (read-modify-write)
// ---------------------------------------------------------------------------
template <int EPI>
__global__ __launch_bounds__(256) void gemm_bt(const u16* __restrict__ A,
                                               const u16* __restrict__ B,
                                               u16* outB, float* outF,
                                               const float* __restrict__ biasF,
                                               const u16* aux0,
                                               const float* auxF,
                                               int N, int K, int lda, int ldb) {
    __shared__ u16 As[128 * 64];
    __shared__ u16 Bs[128 * 64];
    int tid = threadIdx.x;
    int lane = tid & 63;
    int wv = tid >> 6;

    // T1 XCD swizzle (bijective; all grids here have nwg % 8 == 0)
    int gx = gridDim.x, gy = gridDim.y;
    int nwg = gx * gy;
    int bx = blockIdx.x, by = blockIdx.y;
    if ((nwg & 7) == 0) {
        int hw = by * gx + bx;
        int q = nwg >> 3;
        int lg = (hw & 7) * q + (hw >> 3);
        bx = lg % gx;
        by = lg / gx;
    }

    int row0 = by * 128;
    int col0 = bx * 128;
    int wm = (wv >> 1) * 64;
    int wn = (wv & 1) * 64;
    int frow = lane & 15, quad = lane >> 4;

    float4v zero = {0.f, 0.f, 0.f, 0.f};
    float4v acc[4][4];
#pragma unroll
    for (int i = 0; i < 4; ++i)
#pragma unroll
        for (int j = 0; j < 4; ++j) acc[i][j] = zero;

    for (int k0 = 0; k0 < K; k0 += 64) {
#pragma unroll
        for (int it = 0; it < 4; ++it) {
            int base = (wv * 4 + it) * 512;      // element offset (wave-uniform)
            int e = base + lane * 8;
            int r = e >> 6, c = e & 63;
            GLOAD_LDS16(A + (size_t)(row0 + r) * lda + (k0 + c), &As[base]);
            GLOAD_LDS16(B + (size_t)(col0 + r) * ldb + (k0 + c), &Bs[base]);
        }
        __syncthreads();
#pragma unroll
        for (int kk = 0; kk < 64; kk += 32) {
            short8 a_frag[4], b_frag[4];
#pragma unroll
            for (int mi = 0; mi < 4; ++mi)
                a_frag[mi] = *(const short8*)&As[(wm + mi * 16 + frow) * 64 + kk + quad * 8];
#pragma unroll
            for (int ni = 0; ni < 4; ++ni)
                b_frag[ni] = *(const short8*)&Bs[(wn + ni * 16 + frow) * 64 + kk + quad * 8];
#pragma unroll
            for (int mi = 0; mi < 4; ++mi)
#pragma unroll
                for (int ni = 0; ni < 4; ++ni)
                    acc[mi][ni] = __builtin_amdgcn_mfma_f32_16x16x32_bf16(
                        a_frag[mi], b_frag[ni], acc[mi][ni], 0, 0, 0);
        }
        __syncthreads();
    }

#pragma unroll
    for (int mi = 0; mi < 4; ++mi) {
#pragma unroll
        for (int ni = 0; ni < 4; ++ni) {
#pragma unroll
            for (int r = 0; r < 4; ++r) {
                int row = row0 + wm + mi * 16 + quad * 4 + r;
                int col = col0 + wn + ni * 16 + frow;
                size_t g = (size_t)row * N + col;
                float v = acc[mi][ni][r];
                if constexpr (EPI == 0) {
                    outB[g] = f2b(v + biasF[col]);
                } else if constexpr (EPI == 1) {
                    outB[g] = f2b(v + b2f(aux0[g]));
                } else if constexpr (EPI == 2) {
                    float sg = 1.f / (1.f + expf(-v));
                    outB[g] = f2b(sg * b2f(aux0[g]));
                } else if constexpr (EPI == 3) {
                    outF[g] = v + auxF[g];
                } else if constexpr (EPI == 4) {
                    outB[g] = f2b(1.f / (1.f + expf(-v)));
                } else if constexpr (EPI == 5) {
                    float t = v > 0.f ? v : 0.f;
                    outB[g] = f2b(t * t);
                } else if constexpr (EPI == 6) {
                    outF[g] = outF[g] + b2f(aux0[g]) * v;
                }
            }
        }
    }
}

// ---------------------------------------------------------------------------
extern "C" void kernel_launch(void* const* d_in, const int* in_sizes, int n_in,
                              void* d_out, int out_size, void* d_ws, size_t ws_size,
                              hipStream_t stream) {
    (void)in_sizes; (void)n_in; (void)out_size; (void)ws_size;
    const float* x   = (const float*)d_in[0];
    const float* n1w = (const float*)d_in[1];
    // d_in[2] tm_mix_k, d_in[5] tm_key_w are dead in the reference
    const float* tmv = (const float*)d_in[3];
    const float* tmr = (const float*)d_in[4];
    const float* vw  = (const float*)d_in[6];
    const float* rw  = (const float*)d_in[7];
    const float* ow  = (const float*)d_in[8];
    const float* qw  = (const float*)d_in[9];
    const float* qb  = (const float*)d_in[10];
    const float* skw = (const float*)d_in[11];
    const float* skb = (const float*)d_in[12];
    const float* svw = (const float*)d_in[13];
    const float* svb = (const float*)d_in[14];
    const float* sow = (const float*)d_in[15];
    const float* sob = (const float*)d_in[16];
    const float* n2w = (const float*)d_in[17];
    const float* cmk = (const float*)d_in[18];
    const float* cmr = (const float*)d_in[19];
    const float* ckw = (const float*)d_in[20];
    const float* crw = (const float*)d_in[21];
    const float* cvw = (const float*)d_in[22];

    char* W = (char*)d_ws;
    const size_t MB = 1ull << 20;
    u16*   bufA  = (u16*)(W + 0 * MB);     // 16 MB
    u16*   bufB  = (u16*)(W + 16 * MB);    // 16 MB (with C forms 32 MB k2 chunk)
    u16*   bufC  = (u16*)(W + 32 * MB);    // 16 MB
    u16*   bufD  = (u16*)(W + 48 * MB);    // 16 MB (scratch below until 1st gemm)
    // attn scratch INSIDE bufD's slot (freed before bufD's first write):
    double* qv64 = (double*)(W + 48 * MB); // 4 MB  [8192][64] f64
    u16*   Qhi   = (u16*)(W + 52 * MB);    // 1 MB
    u16*   Qlo   = (u16*)(W + 53 * MB);    // 1 MB
    u16*   Khi   = (u16*)(W + 54 * MB);    // 1 MB
    u16*   Klo   = (u16*)(W + 55 * MB);    // 1 MB
    float* Kt4   = (float*)(W + 64 * MB);  // 2 MB  [b][g][key][4]
    float* invn  = (float*)(W + 66 * MB);  // 32 KB
    u16*   ckw16 = (u16*)(W + 68 * MB);    // 8 MB
    u16*   cvw16 = (u16*)(W + 76 * MB);    // 8 MB
    u16*   svw16 = (u16*)(W + 84 * MB);    // 2 MB each below
    u16*   sow16 = (u16*)(W + 86 * MB);
    u16*   vw16  = (u16*)(W + 88 * MB);
    u16*   rw16  = (u16*)(W + 90 * MB);
    u16*   ow16  = (u16*)(W + 92 * MB);
    u16*   crw16 = (u16*)(W + 94 * MB);    // peak 96 MB
    float* x1    = (float*)d_out;          // 32 MB f32, accumulated in place
    _Float16* scF = (_Float16*)d_out;      // scores scratch (32 MB) BEFORE x1 use

    dim3 blk(256);
    dim3 gN1024(8, 64);
    dim3 gN2048(16, 64);
    const int NW = 512;

    // weight prep
    wcvt<<<NW, blk, 0, stream>>>(svw, svw16, 1024 * 1024);
    wcvt<<<NW, blk, 0, stream>>>(sow, sow16, 1024 * 1024);
    wcvt<<<NW, blk, 0, stream>>>(vw,  vw16,  1024 * 1024);
    wcvt<<<NW, blk, 0, stream>>>(rw,  rw16,  1024 * 1024);
    wcvt<<<NW, blk, 0, stream>>>(ow,  ow16,  1024 * 1024);
    wcvt<<<NW, blk, 0, stream>>>(crw, crw16, 1024 * 1024);
    wcvt<<<NW, blk, 0, stream>>>(ckw, ckw16, 4096 * 1024);
    wcvt<<<NW, blk, 0, stream>>>(cvw, cvw16, 1024 * 4096);

    // --- time-mix ---
    mix2out<<<8192, blk, 0, stream>>>(x, n1w, tmv, tmr, bufA, bufC);  // vin, rin
    kproj<<<8192, blk, 0, stream>>>(x, n1w, skw, skb, qw, qb, Kt4, invn,
                                    qv64, Qhi, Qlo, Khi, Klo);
    for (int bb = 0; bb < 2; ++bb) {
        size_t o = (size_t)bb * 4096 * 64;
        score_gemm<<<dim3(32, 32), blk, 0, stream>>>(Qhi + o, Qlo + o,
                                                     Khi + o, Klo + o, scF);
        attn_sel<<<4096, dim3(64), 0, stream>>>(x, n1w, scF, qv64, Kt4, invn,
                                                bufB, bb * 4096);
    }
    // t = y @ sa_v_w^T + svb
    gemm_bt<0><<<gN1024, blk, 0, stream>>>(bufB, svw16, bufD, nullptr, svb, nullptr, nullptr, 1024, 1024, 1024, 1024);
    // attnO = t @ sa_o_w^T + sob  (overwrites y, dead)
    gemm_bt<0><<<gN1024, blk, 0, stream>>>(bufD, sow16, bufB, nullptr, sob, nullptr, nullptr, 1024, 1024, 1024, 1024);
    // z = vin @ tm_value_w^T + attnO   (in-place over attnO)
    gemm_bt<1><<<gN1024, blk, 0, stream>>>(bufA, vw16, bufB, nullptr, nullptr, bufB, nullptr, 1024, 1024, 1024, 1024);
    // rkv = sigmoid(rin @ tm_recept_w^T) * z   (in-place over z)
    gemm_bt<2><<<gN1024, blk, 0, stream>>>(bufC, rw16, bufB, nullptr, nullptr, bufB, nullptr, 1024, 1024, 1024, 1024);
    // x1 = x + rkv @ tm_out_w^T   (f32, into d_out — scores scratch is dead now)
    gemm_bt<3><<<gN1024, blk, 0, stream>>>(bufB, ow16, nullptr, x1, nullptr, nullptr, x, 1024, 1024, 1024, 1024);

    // --- channel-mix ---
    mix2out<<<8192, blk, 0, stream>>>(x1, n2w, cmk, cmr, bufA, bufC);  // kin2, rin2
    // sig2 = sigmoid(rin2 @ cm_recept_w^T) -> D
    gemm_bt<4><<<gN1024, blk, 0, stream>>>(bufC, crw16, bufD, nullptr, nullptr, nullptr, nullptr, 1024, 1024, 1024, 1024);
    // 2 chunks of 2048 DI-columns; k2 chunk (32 MB bf16) spans bufB..bufC
    for (int c = 0; c < 2; ++c) {
        const u16* ckw_c = ckw16 + (size_t)c * 2048 * 1024;  // rows c*2048.. of (4096,1024)
        const u16* cvw_c = cvw16 + (size_t)c * 2048;         // cols c*2048.. of (1024,4096)
        gemm_bt<5><<<gN2048, blk, 0, stream>>>(bufA, ckw_c, bufB, nullptr, nullptr, nullptr, nullptr,
                                               2048, 1024, 1024, 1024);
        gemm_bt<6><<<gN1024, blk, 0, stream>>>(bufB, cvw_c, nullptr, x1, nullptr, bufD, nullptr,
                                               1024, 2048, 2048, 4096);
    }
}